// Round 10
// baseline (463.752 us; speedup 1.0000x reference)
//
#include <hip/hip_runtime.h>

typedef _Float16 f16;
typedef _Float16 f16x8 __attribute__((ext_vector_type(8)));
typedef float f32x4 __attribute__((ext_vector_type(4)));

#define N_ATOMS 50000
#define NEIGH   12
#define NEDGE   (N_ATOMS * NEIGH)
#define NCRYS   500
#define NBLK    196  // ceil(50000/256)

// ---------------- layer-1 GEMM: [P|Q] = GBF(A) @ Wcat^T ----------------
// Barrier-free wave-independent form. Cross-round evidence (R3/R5/R6/R8/R9):
// every __syncthreads()-per-tile variant is pinned at ~2.3us/K-tile because the
// barrier's implicit vmcnt(0) drains in-flight B/A loads every tile (m97-ceiling
// mechanism). Here each wave owns 64 rows x 128 cols: no LDS, no barriers ->
// only counted waitcnts; B prefetched 1 tile ahead (~950cyc distance), d 2 ahead.
// exp duplication only 2x (col-split). All reg arrays statically indexed.
template <int MODE, int K>
__device__ __forceinline__ void gemm1_body(
    const float* __restrict__ Asrc, const f16* __restrict__ Wcat,
    f16* __restrict__ P, f16* __restrict__ Q, int n) {
  constexpr int CIN = (MODE == 1) ? 12 : 144;
  constexpr int NT = K / 32;
  constexpr float G2I = (MODE == 1) ? 25.0f : 16.0f;        // 1/gamma^2
  constexpr float DLT = (MODE == 1) ? (8.0f / 39.0f) : (2.0f / 7.0f);
  constexpr float C1 = 2.0f * G2I * DLT;
  constexpr float C2 = G2I * DLT * DLT;
  constexpr int RUN = (MODE == 1) ? 4 : 8;  // bond 4-runs: exp(C1*u) near f32 max
  const float S = __expf(-2.0f * C2);

  const int lane = threadIdx.x & 63;
  const int wid = threadIdx.x >> 6;
  const int wr = wid & 1;   // 64-row strip
  const int wc = wid >> 1;  // 128-col strip (0 -> P, 1 -> Q)
  const int row0 = blockIdx.x * 128 + wr * 64;
  const int r16 = lane & 15;
  const int kb = lane >> 4;

  int rm[4];
#pragma unroll
  for (int m = 0; m < 4; ++m) {
    int r = row0 + m * 16 + r16;
    rm[m] = (r < n) ? r : (n - 1);
  }
  const f16* wbase = Wcat + (size_t)(wc * 128 + r16) * K + kb * 8;

  f32x4 acc[4][8];
#pragma unroll
  for (int m = 0; m < 4; ++m)
#pragma unroll
    for (int q = 0; q < 8; ++q) acc[m][q] = (f32x4)0.f;

  auto dload = [&](int t, float* dd) {
    int kg = t * 32 + kb * 8;
    int jn = (MODE == 1) ? kg / 40 : (kg >> 3);
#pragma unroll
    for (int m = 0; m < 4; ++m) dd[m] = Asrc[(size_t)rm[m] * CIN + jn];
  };
  auto bload = [&](int t, f16x8* bb) {
#pragma unroll
    for (int q = 0; q < 8; ++q)
      bb[q] = *(const f16x8*)(wbase + (size_t)q * 16 * K + t * 32);
  };

  float dA[4], dB[4], dC[4];
  f16x8 bA[8], bB[8];
  dload(0, dA);
  bload(0, bA);
  if (NT > 1) dload(1, dB);

  for (int t = 0; t < NT; ++t) {
    if (t + 1 < NT) bload(t + 1, bB);
    if (t + 2 < NT) dload(t + 2, dC);
    // A-frags: 8 GBF values per m from one d (8-run never crosses a filter
    // group: 40%8==0 for bond; angle groups are exactly 8 wide)
    int kg0 = t * 32 + kb * 8;
    f16x8 a[4];
#pragma unroll
    for (int m = 0; m < 4; ++m) {
      float d = dA[m];
      int kk0;
      if constexpr (MODE == 1) {
        int jn = kg0 / 40;
        kk0 = kg0 - jn * 40;
      } else {
        kk0 = 0;
      }
      f16 v[8];
#pragma unroll
      for (int h = 0; h < 8 / RUN; ++h) {
        float f0 = (float)(kk0 + h * RUN) * DLT + (MODE == 2 ? -1.0f : 0.0f);
        float u = d - f0;
        float g = __expf(-G2I * u * u);
        float ratio = __expf(C1 * u - C2);
        v[h * RUN] = (f16)g;
#pragma unroll
        for (int j = 1; j < RUN; ++j) {
          g *= ratio;
          ratio *= S;
          v[h * RUN + j] = (f16)g;
        }
      }
      a[m] = *(const f16x8*)v;
    }
#pragma unroll
    for (int m = 0; m < 4; ++m)
#pragma unroll
      for (int q = 0; q < 8; ++q)
        acc[m][q] =
            __builtin_amdgcn_mfma_f32_16x16x32_f16(a[m], bA[q], acc[m][q], 0, 0, 0);
#pragma unroll
    for (int m = 0; m < 4; ++m) {
      dA[m] = dB[m];
      dB[m] = dC[m];
    }
#pragma unroll
    for (int q = 0; q < 8; ++q) bA[q] = bB[q];
  }

  const int crow = (lane >> 4) * 4;
  const int ccol = lane & 15;
  f16* outp = wc ? Q : P;
#pragma unroll
  for (int m = 0; m < 4; ++m) {
#pragma unroll
    for (int r = 0; r < 4; ++r) {
      int row = row0 + m * 16 + crow + r;
      if (row < n) {
#pragma unroll
        for (int q = 0; q < 8; ++q)
          outp[(size_t)row * 128 + q * 16 + ccol] = (f16)acc[m][q][r];
      }
    }
  }
}

// grid (391, 2): y=0 angle (K=1152), y=1 bond (K=480) — co-resident, tail overlap
__global__ __launch_bounds__(256) void gemm1w(
    const float* __restrict__ angle, const f16* __restrict__ Wa,
    f16* __restrict__ Pa, f16* __restrict__ Qa,
    const float* __restrict__ bond, const f16* __restrict__ Wb,
    f16* __restrict__ Pb, f16* __restrict__ Qb, int n) {
  if (blockIdx.y == 0)
    gemm1_body<2, 1152>(angle, Wa, Pa, Qa, n);
  else
    gemm1_body<1, 480>(bond, Wb, Pb, Qb, n);
}

// ---------------- layers 2-3 register GEMM: dst.x = relu([agg|x]@W^T + b) ----
__global__ __launch_bounds__(256) void gemmL_reg(
    const f16* __restrict__ srcB, const f16* __restrict__ srcA,
    f16* __restrict__ dstB, f16* __restrict__ dstA, const f16* __restrict__ Wall,
    const float* __restrict__ bb, const float* __restrict__ ba, int lidx, int n) {
  const int path = blockIdx.y;
  const f16* src = path ? srcA : srcB;
  f16* dst = path ? dstA : dstB;
  const f16* W = Wall + (size_t)(path * 2 + lidx) * 32768;
  const float* bias = (path ? ba : bb) + lidx * 128;

  const int lane = threadIdx.x & 63;
  const int wid = threadIdx.x >> 6;
  const int wr = wid & 1;
  const int wc = wid >> 1;
  const int row0 = blockIdx.x * 128;
  const int r16 = lane & 15;
  const int kb = lane >> 4;

  int rm[4];
#pragma unroll
  for (int m = 0; m < 4; ++m) {
    int r = row0 + wr * 64 + m * 16 + r16;
    rm[m] = (r < n) ? r : (n - 1);
  }
  const f16* wb[4];
#pragma unroll
  for (int q = 0; q < 4; ++q)
    wb[q] = W + (size_t)(wc * 64 + q * 16 + r16) * 256 + kb * 8;

  f32x4 acc[4][4];
#pragma unroll
  for (int m = 0; m < 4; ++m)
#pragma unroll
    for (int q = 0; q < 4; ++q) acc[m][q] = (f32x4)0.f;

#pragma unroll
  for (int t = 0; t < 8; ++t) {
    f16x8 a[4], b[4];
#pragma unroll
    for (int m = 0; m < 4; ++m)
      a[m] = *(const f16x8*)&src[(size_t)rm[m] * 256 + t * 32 + kb * 8];
#pragma unroll
    for (int q = 0; q < 4; ++q) b[q] = *(const f16x8*)(wb[q] + t * 32);
#pragma unroll
    for (int m = 0; m < 4; ++m)
#pragma unroll
      for (int q = 0; q < 4; ++q)
        acc[m][q] =
            __builtin_amdgcn_mfma_f32_16x16x32_f16(a[m], b[q], acc[m][q], 0, 0, 0);
  }

  const int crow = (lane >> 4) * 4;
  const int ccol = lane & 15;
#pragma unroll
  for (int m = 0; m < 4; ++m) {
#pragma unroll
    for (int r = 0; r < 4; ++r) {
      int row = row0 + wr * 64 + m * 16 + crow + r;
      if (row < n) {
#pragma unroll
        for (int q = 0; q < 4; ++q) {
          int col = wc * 64 + q * 16 + ccol;
          float v = acc[m][q][r] + bias[col];
          dst[(size_t)row * 256 + 128 + col] = (f16)fmaxf(v, 0.0f);
        }
      }
    }
  }
}

// ---------------- weight conversion ----------------
__global__ void cvtW(const float* __restrict__ Wl, const float* __restrict__ Wr,
                     f16* __restrict__ outp, int K) {
  int c = blockIdx.y;
  int k = blockIdx.x * 256 + threadIdx.x;
  if (k < K)
    outp[(size_t)c * K + k] =
        (f16)((c < 128) ? Wl[(size_t)c * K + k] : Wr[(size_t)(c - 128) * K + k]);
}

__global__ void cvtW_small(const float* __restrict__ Wl_b, const float* __restrict__ Wr_b,
                           const float* __restrict__ Wl_a, const float* __restrict__ Wr_a,
                           f16* __restrict__ outp) {
  int idx = blockIdx.x * 256 + threadIdx.x;  // 4*128*256
  int l = idx >> 15;
  int c = (idx >> 8) & 127;
  int k = idx & 255;
  const float* Wl = (l < 2) ? Wl_b + (size_t)l * 16384 : Wl_a + (size_t)(l - 2) * 16384;
  const float* Wr = (l < 2) ? Wr_b + (size_t)l * 16384 : Wr_a + (size_t)(l - 2) * 16384;
  float v = (k < 128) ? Wl[(size_t)c * 128 + k] : Wr[(size_t)c * 128 + (k - 128)];
  outp[idx] = (f16)v;
}

// ---------------- CSR build ----------------
__global__ void k_count(const int* __restrict__ nbr, int* __restrict__ deg) {
  int e = blockIdx.x * 256 + threadIdx.x;
  if (e < NEDGE) atomicAdd(&deg[nbr[e]], 1);
}
__global__ void k_scan1(const int* __restrict__ deg, int* __restrict__ rowptr,
                        int* __restrict__ bsum) {
  __shared__ int s[256];
  int t = threadIdx.x, i = blockIdx.x * 256 + t;
  int v = (i < N_ATOMS) ? deg[i] : 0;
  s[t] = v;
  __syncthreads();
  for (int off = 1; off < 256; off <<= 1) {
    int x = (t >= off) ? s[t - off] : 0;
    __syncthreads();
    s[t] += x;
    __syncthreads();
  }
  if (i < N_ATOMS) rowptr[i] = s[t] - v;
  if (t == 255) bsum[blockIdx.x] = s[255];
}
__global__ void k_scan2(int* __restrict__ bsum) {
  __shared__ int s[256];
  int t = threadIdx.x;
  int v = (t < NBLK) ? bsum[t] : 0;
  s[t] = v;
  __syncthreads();
  for (int off = 1; off < 256; off <<= 1) {
    int x = (t >= off) ? s[t - off] : 0;
    __syncthreads();
    s[t] += x;
    __syncthreads();
  }
  if (t < NBLK) bsum[t] = s[t] - v;
}
__global__ void k_scan3(int* __restrict__ rowptr, const int* __restrict__ bsum) {
  int i = blockIdx.x * 256 + threadIdx.x;
  if (i < N_ATOMS) rowptr[i] += bsum[blockIdx.x];
  if (i == 0) rowptr[N_ATOMS] = NEDGE;
}
__global__ void k_fill(const int* __restrict__ nbr, const int* __restrict__ rowptr,
                       int* __restrict__ cursor, int* __restrict__ eidx) {
  int e = blockIdx.x * 256 + threadIdx.x;
  if (e < NEDGE) {
    int dst = nbr[e];
    int pos = rowptr[dst] + atomicAdd(&cursor[dst], 1);
    eidx[pos] = e / NEIGH;
  }
}

// ---------------- layer-1 finalize: x = relu(mean_j P[src_j] + b + Q) ----------------
__global__ __launch_bounds__(256) void gather_fin1(
    const f16* __restrict__ Pb, const f16* __restrict__ Qb,
    const f16* __restrict__ Pa, const f16* __restrict__ Qa,
    const int* __restrict__ rowptr, const int* __restrict__ eidx,
    const float* __restrict__ bias_b, const float* __restrict__ bias_a,
    f16* __restrict__ axb, f16* __restrict__ axa) {
  const int path = blockIdx.y;
  const f16* P = path ? Pa : Pb;
  const f16* Q = path ? Qa : Qb;
  const float* bias = path ? bias_a : bias_b;
  f16* ax = path ? axa : axb;
  const int t = threadIdx.x;
  const int a = blockIdx.x * 16 + (t >> 4);
  const int g = (t & 15) * 8;
  const int s0 = rowptr[a], s1 = rowptr[a + 1];
  float acc[8];
#pragma unroll
  for (int u = 0; u < 8; ++u) acc[u] = 0.f;
  int j = s0;
  for (; j + 8 <= s1; j += 8) {
    int e[8];
#pragma unroll
    for (int u = 0; u < 8; ++u) e[u] = eidx[j + u];
    f16x8 v[8];
#pragma unroll
    for (int u = 0; u < 8; ++u) v[u] = *(const f16x8*)&P[(size_t)e[u] * 128 + g];
#pragma unroll
    for (int u = 0; u < 8; ++u)
#pragma unroll
      for (int c = 0; c < 8; ++c) acc[c] += (float)v[u][c];
  }
  for (; j + 4 <= s1; j += 4) {
    int e0 = eidx[j], e1 = eidx[j + 1], e2 = eidx[j + 2], e3 = eidx[j + 3];
    f16x8 v0 = *(const f16x8*)&P[(size_t)e0 * 128 + g];
    f16x8 v1 = *(const f16x8*)&P[(size_t)e1 * 128 + g];
    f16x8 v2 = *(const f16x8*)&P[(size_t)e2 * 128 + g];
    f16x8 v3 = *(const f16x8*)&P[(size_t)e3 * 128 + g];
#pragma unroll
    for (int c = 0; c < 8; ++c)
      acc[c] += ((float)v0[c] + (float)v1[c]) + ((float)v2[c] + (float)v3[c]);
  }
  for (; j < s1; ++j) {
    f16x8 v = *(const f16x8*)&P[(size_t)eidx[j] * 128 + g];
#pragma unroll
    for (int c = 0; c < 8; ++c) acc[c] += (float)v[c];
  }
  f16x8 q = *(const f16x8*)&Q[(size_t)a * 128 + g];
  float inv = 1.0f / fmaxf((float)(s1 - s0), 1.0f);
  f16 outv[8];
#pragma unroll
  for (int u = 0; u < 8; ++u) {
    float v = acc[u] * inv + bias[g + u] + (float)q[u];
    outv[u] = (f16)fmaxf(v, 0.0f);
  }
  *(f16x8*)&ax[(size_t)a * 256 + 128 + g] = *(const f16x8*)outv;
}

// ---------------- layers 2-3 aggregation: agg half <- mean_j x[src_j] ----------------
__global__ __launch_bounds__(256) void gather_mean(
    f16* __restrict__ axb, f16* __restrict__ axa,
    const int* __restrict__ rowptr, const int* __restrict__ eidx) {
  f16* ax = blockIdx.y ? axa : axb;
  const int t = threadIdx.x;
  const int a = blockIdx.x * 16 + (t >> 4);
  const int g = (t & 15) * 8;
  const int s0 = rowptr[a], s1 = rowptr[a + 1];
  float acc[8];
#pragma unroll
  for (int u = 0; u < 8; ++u) acc[u] = 0.f;
  int j = s0;
  for (; j + 8 <= s1; j += 8) {
    int e[8];
#pragma unroll
    for (int u = 0; u < 8; ++u) e[u] = eidx[j + u];
    f16x8 v[8];
#pragma unroll
    for (int u = 0; u < 8; ++u)
      v[u] = *(const f16x8*)&ax[(size_t)e[u] * 256 + 128 + g];
#pragma unroll
    for (int u = 0; u < 8; ++u)
#pragma unroll
      for (int c = 0; c < 8; ++c) acc[c] += (float)v[u][c];
  }
  for (; j + 4 <= s1; j += 4) {
    int e0 = eidx[j], e1 = eidx[j + 1], e2 = eidx[j + 2], e3 = eidx[j + 3];
    f16x8 v0 = *(const f16x8*)&ax[(size_t)e0 * 256 + 128 + g];
    f16x8 v1 = *(const f16x8*)&ax[(size_t)e1 * 256 + 128 + g];
    f16x8 v2 = *(const f16x8*)&ax[(size_t)e2 * 256 + 128 + g];
    f16x8 v3 = *(const f16x8*)&ax[(size_t)e3 * 256 + 128 + g];
#pragma unroll
    for (int c = 0; c < 8; ++c)
      acc[c] += ((float)v0[c] + (float)v1[c]) + ((float)v2[c] + (float)v3[c]);
  }
  for (; j < s1; ++j) {
    f16x8 v = *(const f16x8*)&ax[(size_t)eidx[j] * 256 + 128 + g];
#pragma unroll
    for (int c = 0; c < 8; ++c) acc[c] += (float)v[c];
  }
  float inv = 1.0f / fmaxf((float)(s1 - s0), 1.0f);
  f16 outv[8];
#pragma unroll
  for (int u = 0; u < 8; ++u) outv[u] = (f16)(acc[u] * inv);
  *(f16x8*)&ax[(size_t)a * 256 + g] = *(const f16x8*)outv;
}

// ---------------- head: pool -> mlp -> mlp -> fc ----------------
__global__ __launch_bounds__(256) void head_kernel(
    const f16* __restrict__ axb, const f16* __restrict__ axa,
    const int* __restrict__ crys, const float* __restrict__ W_mlp,
    const float* __restrict__ b_mlp, const float* __restrict__ W_fc,
    const float* __restrict__ b_fc, float* __restrict__ outp) {
  __shared__ float sh0[256], sh1[256];
  const int cry = blockIdx.x, c = threadIdx.x;
  const int s = crys[2 * cry], e = crys[2 * cry + 1];
  const f16* src = (c < 128) ? axb : axa;
  const int ch = c & 127;
  float sum = 0.f;
  for (int r = s; r < e; ++r) sum += (float)src[(size_t)r * 256 + 128 + ch];
  sh0[c] = sum / fmaxf((float)(e - s), 1.0f);
  __syncthreads();
  {
    const float* wrow = W_mlp + (size_t)c * 256;
    float s2 = b_mlp[c];
#pragma unroll 8
    for (int k = 0; k < 256; k += 4) {
      float4 w = *(const float4*)&wrow[k];
      s2 += sh0[k] * w.x + sh0[k + 1] * w.y + sh0[k + 2] * w.z + sh0[k + 3] * w.w;
    }
    sh1[c] = s2;
  }
  __syncthreads();
  {
    const float* wrow = W_mlp + 65536 + (size_t)c * 256;
    float s2 = b_mlp[256 + c];
#pragma unroll 8
    for (int k = 0; k < 256; k += 4) {
      float4 w = *(const float4*)&wrow[k];
      s2 += sh1[k] * w.x + sh1[k + 1] * w.y + sh1[k + 2] * w.z + sh1[k + 3] * w.w;
    }
    sh0[c] = s2;
  }
  __syncthreads();
  if (c < 2) {
    const float* wrow = W_fc + c * 256;
    float s2 = b_fc[c];
    for (int k = 0; k < 256; ++k) s2 += sh0[k] * wrow[k];
    outp[cry * 2 + c] = s2;
  }
}

extern "C" void kernel_launch(void* const* d_in, const int* in_sizes, int n_in,
                              void* d_out, int out_size, void* d_ws, size_t ws_size,
                              hipStream_t stream) {
  const float* bond  = (const float*)d_in[0];
  const float* angle = (const float*)d_in[1];
  const int*   nbr   = (const int*)d_in[3];
  const int*   crys  = (const int*)d_in[4];
  const float* Wl_b1 = (const float*)d_in[5];
  const float* Wr_b1 = (const float*)d_in[6];
  const float* b_b1  = (const float*)d_in[7];
  const float* Wl_a1 = (const float*)d_in[8];
  const float* Wr_a1 = (const float*)d_in[9];
  const float* b_a1  = (const float*)d_in[10];
  const float* Wl_b  = (const float*)d_in[11];
  const float* Wr_b  = (const float*)d_in[12];
  const float* b_b   = (const float*)d_in[13];
  const float* Wl_a  = (const float*)d_in[14];
  const float* Wr_a  = (const float*)d_in[15];
  const float* b_a   = (const float*)d_in[16];
  const float* W_mlp = (const float*)d_in[17];
  const float* b_mlp = (const float*)d_in[18];
  const float* W_fc  = (const float*)d_in[19];
  const float* b_fc  = (const float*)d_in[20];

  char* w = (char*)d_ws;
  auto alloc = [&](size_t bytes) {
    void* p = (void*)w;
    w += (bytes + 255) & ~(size_t)255;
    return p;
  };
  // ping-pong activation buffers; layer-1 P/Q alias the B buffers
  f16* axbA = (f16*)alloc((size_t)N_ATOMS * 256 * 2);
  f16* axaA = (f16*)alloc((size_t)N_ATOMS * 256 * 2);
  f16* axbB = (f16*)alloc((size_t)N_ATOMS * 256 * 2);
  f16* axaB = (f16*)alloc((size_t)N_ATOMS * 256 * 2);
  f16* Pb = axbB;
  f16* Qb = axbB + (size_t)N_ATOMS * 128;
  f16* Pa = axaB;
  f16* Qa = axaB + (size_t)N_ATOMS * 128;
  f16* Wb1c = (f16*)alloc((size_t)256 * 480 * 2);
  f16* Wa1c = (f16*)alloc((size_t)256 * 1152 * 2);
  f16* Wsm  = (f16*)alloc((size_t)4 * 128 * 256 * 2);
  // deg+cursor as ONE contiguous block: the single memset must cover BOTH
  // (0xAA re-poison between timed replays otherwise leaves cursor garbage).
  int* deg    = (int*)alloc((size_t)2 * N_ATOMS * 4);
  int* cursor = deg + N_ATOMS;
  int* rowptr = (int*)alloc((size_t)(N_ATOMS + 1) * 4);
  int* eidx   = (int*)alloc((size_t)NEDGE * 4);
  int* bsum   = (int*)alloc(256 * 4);

  // weights -> fp16
  cvtW<<<dim3(2, 256), 256, 0, stream>>>(Wl_b1, Wr_b1, Wb1c, 480);
  cvtW<<<dim3(5, 256), 256, 0, stream>>>(Wl_a1, Wr_a1, Wa1c, 1152);
  cvtW_small<<<512, 256, 0, stream>>>(Wl_b, Wr_b, Wl_a, Wr_a, Wsm);

  // CSR build
  hipMemsetAsync(deg, 0, (size_t)2 * N_ATOMS * 4, stream);
  k_count<<<(NEDGE + 255) / 256, 256, 0, stream>>>(nbr, deg);
  k_scan1<<<NBLK, 256, 0, stream>>>(deg, rowptr, bsum);
  k_scan2<<<1, 256, 0, stream>>>(bsum);
  k_scan3<<<NBLK, 256, 0, stream>>>(rowptr, bsum);
  k_fill<<<(NEDGE + 255) / 256, 256, 0, stream>>>(nbr, rowptr, cursor, eidx);

  const int GG = (N_ATOMS + 127) / 128;  // 391
  const int AG = N_ATOMS / 16;           // 3125

  // layer 1: barrier-free wave-GEMM, angle+bond in one dispatch
  gemm1w<<<dim3(GG, 2), 256, 0, stream>>>(angle, Wa1c, Pa, Qa,
                                          bond, Wb1c, Pb, Qb, N_ATOMS);
  gather_fin1<<<dim3(AG, 2), 256, 0, stream>>>(Pb, Qb, Pa, Qa, rowptr, eidx,
                                               b_b1, b_a1, axbA, axaA);

  // layers 2-3 (aggregate-then-project, ping-pong A -> B -> A)
  gather_mean<<<dim3(AG, 2), 256, 0, stream>>>(axbA, axaA, rowptr, eidx);
  gemmL_reg<<<dim3(GG, 2), 256, 0, stream>>>(axbA, axaA, axbB, axaB, Wsm, b_b, b_a,
                                             0, N_ATOMS);
  gather_mean<<<dim3(AG, 2), 256, 0, stream>>>(axbB, axaB, rowptr, eidx);
  gemmL_reg<<<dim3(GG, 2), 256, 0, stream>>>(axbB, axaB, axbA, axaA, Wsm, b_b, b_a,
                                             1, N_ATOMS);

  // head
  head_kernel<<<NCRYS, 256, 0, stream>>>(axbA, axaA, crys, W_mlp, b_mlp, W_fc, b_fc,
                                         (float*)d_out);
}

// Round 11
// 442.461 us; speedup vs baseline: 1.0481x; 1.0481x over previous
//
#include <hip/hip_runtime.h>

typedef _Float16 f16;
typedef _Float16 f16x8 __attribute__((ext_vector_type(8)));
typedef float f32x4 __attribute__((ext_vector_type(4)));

#define N_ATOMS 50000
#define NEIGH   12
#define NEDGE   (N_ATOMS * NEIGH)
#define NCRYS   500
#define NBLK    196  // ceil(50000/256)

__device__ __forceinline__ void gld_lds16(const void* g, void* l) {
  __builtin_amdgcn_global_load_lds(
      (const __attribute__((address_space(1))) unsigned int*)g,
      (__attribute__((address_space(3))) unsigned int*)l, 16, 0, 0);
}

// ---------------- layer-1 GEMM (R6 form — measured best: 80us angle, ~25us bond) ----
// BM=256 rows/block, BN=128 cols; blockIdx.y: 0 -> Wl half (P), 1 -> Wr half (Q).
// MODE 1: bond fp32 [N][12], GBF K=480 (40 filters). MODE 2: angle fp32 [N][144], K=1152.
template <int MODE, int K>
__global__ __launch_bounds__(512) void gemm1(
    const float* __restrict__ Asrc, const f16* __restrict__ Wcat,
    f16* __restrict__ P, f16* __restrict__ Q, int n) {
  __shared__ __align__(16) f16 As[2][4][256][8];  // 32 KB
  __shared__ __align__(16) f16 Bs[2][4][128][8];  // 16 KB
  const int tid = threadIdx.x;
  const int lane = tid & 63;
  const int wid = tid >> 6;
  const int wr = wid >> 1;  // 0..3 (64-row strip)
  const int wc = wid & 1;   // 0..1 (64-col strip)
  const int row0 = blockIdx.x * 256;
  const int half = blockIdx.y;
  const f16* Wh = Wcat + (size_t)half * 128 * K;
  f16* outp = half ? Q : P;

  const int bcol = tid & 127;
  const int bkb = tid >> 7;  // 0..3
  const int sArow = tid & 255;
  const int sAkb0 = tid >> 8;  // 0..1 (+2 on pass 1)
  int arow = row0 + sArow;
  if (arow >= n) arow = n - 1;

  f32x4 acc[4][4];
#pragma unroll
  for (int m = 0; m < 4; ++m)
#pragma unroll
    for (int q = 0; q < 4; ++q) acc[m][q] = (f32x4)0.f;

  auto stage = [&](int buf, int k0) {
    gld_lds16(Wh + (size_t)bcol * K + k0 + bkb * 8, &Bs[buf][bkb][bcol][0]);
#pragma unroll
    for (int p = 0; p < 2; ++p) {
      int kb = sAkb0 + 2 * p;
      int kg0 = k0 + kb * 8;
      f16 v[8];
      if constexpr (MODE == 1) {
        int jn = kg0 / 40;  // 40 % 8 == 0: 8-block never crosses a filter group
        int kk0 = kg0 - jn * 40;
        float d = Asrc[arow * NEIGH + jn];
#pragma unroll
        for (int j = 0; j < 8; ++j) {
          float t = d - (kk0 + j) * (8.0f / 39.0f);
          v[j] = (f16)__expf(-t * t * 25.0f);  // gamma = 8/40
        }
      } else {
        int jn = kg0 >> 3;
        float d = Asrc[arow * 144 + jn];
#pragma unroll
        for (int j = 0; j < 8; ++j) {
          float t = d - (-1.0f + j * (2.0f / 7.0f));
          v[j] = (f16)__expf(-t * t * 16.0f);  // gamma = 2/8
        }
      }
      *(f16x8*)&As[buf][kb][sArow][0] = *(const f16x8*)v;
    }
  };

  constexpr int NT = K / 32;
  stage(0, 0);
  __syncthreads();
  int buf = 0;
  for (int t = 0; t < NT; ++t) {
    if (t + 1 < NT) stage(buf ^ 1, (t + 1) * 32);
    const int kb = lane >> 4;
    const int r16 = lane & 15;
    f16x8 a[4], b[4];
#pragma unroll
    for (int m = 0; m < 4; ++m)
      a[m] = *(const f16x8*)&As[buf][kb][wr * 64 + m * 16 + r16][0];
#pragma unroll
    for (int q = 0; q < 4; ++q)
      b[q] = *(const f16x8*)&Bs[buf][kb][wc * 64 + q * 16 + r16][0];
#pragma unroll
    for (int m = 0; m < 4; ++m)
#pragma unroll
      for (int q = 0; q < 4; ++q)
        acc[m][q] =
            __builtin_amdgcn_mfma_f32_16x16x32_f16(a[m], b[q], acc[m][q], 0, 0, 0);
    __syncthreads();
    buf ^= 1;
  }

  const int crow = (lane >> 4) * 4;
  const int ccol = lane & 15;
#pragma unroll
  for (int m = 0; m < 4; ++m) {
#pragma unroll
    for (int r = 0; r < 4; ++r) {
      int row = row0 + wr * 64 + m * 16 + crow + r;
      if (row < n) {
#pragma unroll
        for (int q = 0; q < 4; ++q)
          outp[(size_t)row * 128 + wc * 64 + q * 16 + ccol] = (f16)acc[m][q][r];
      }
    }
  }
}

// ---------------- layers 2-3 register GEMM: dst.x = relu([agg|x]@W^T + b) ----
__global__ __launch_bounds__(256) void gemmL_reg(
    const f16* __restrict__ srcB, const f16* __restrict__ srcA,
    f16* __restrict__ dstB, f16* __restrict__ dstA, const f16* __restrict__ Wall,
    const float* __restrict__ bb, const float* __restrict__ ba, int lidx, int n) {
  const int path = blockIdx.y;
  const f16* src = path ? srcA : srcB;
  f16* dst = path ? dstA : dstB;
  const f16* W = Wall + (size_t)(path * 2 + lidx) * 32768;
  const float* bias = (path ? ba : bb) + lidx * 128;

  const int lane = threadIdx.x & 63;
  const int wid = threadIdx.x >> 6;
  const int wr = wid & 1;
  const int wc = wid >> 1;
  const int row0 = blockIdx.x * 128;
  const int r16 = lane & 15;
  const int kb = lane >> 4;

  int rm[4];
#pragma unroll
  for (int m = 0; m < 4; ++m) {
    int r = row0 + wr * 64 + m * 16 + r16;
    rm[m] = (r < n) ? r : (n - 1);
  }
  const f16* wb[4];
#pragma unroll
  for (int q = 0; q < 4; ++q)
    wb[q] = W + (size_t)(wc * 64 + q * 16 + r16) * 256 + kb * 8;

  f32x4 acc[4][4];
#pragma unroll
  for (int m = 0; m < 4; ++m)
#pragma unroll
    for (int q = 0; q < 4; ++q) acc[m][q] = (f32x4)0.f;

#pragma unroll
  for (int t = 0; t < 8; ++t) {
    f16x8 a[4], b[4];
#pragma unroll
    for (int m = 0; m < 4; ++m)
      a[m] = *(const f16x8*)&src[(size_t)rm[m] * 256 + t * 32 + kb * 8];
#pragma unroll
    for (int q = 0; q < 4; ++q) b[q] = *(const f16x8*)(wb[q] + t * 32);
#pragma unroll
    for (int m = 0; m < 4; ++m)
#pragma unroll
      for (int q = 0; q < 4; ++q)
        acc[m][q] =
            __builtin_amdgcn_mfma_f32_16x16x32_f16(a[m], b[q], acc[m][q], 0, 0, 0);
  }

  const int crow = (lane >> 4) * 4;
  const int ccol = lane & 15;
#pragma unroll
  for (int m = 0; m < 4; ++m) {
#pragma unroll
    for (int r = 0; r < 4; ++r) {
      int row = row0 + wr * 64 + m * 16 + crow + r;
      if (row < n) {
#pragma unroll
        for (int q = 0; q < 4; ++q) {
          int col = wc * 64 + q * 16 + ccol;
          float v = acc[m][q][r] + bias[col];
          dst[(size_t)row * 256 + 128 + col] = (f16)fmaxf(v, 0.0f);
        }
      }
    }
  }
}

// ---------------- weight conversion ----------------
__global__ void cvtW(const float* __restrict__ Wl, const float* __restrict__ Wr,
                     f16* __restrict__ outp, int K) {
  int c = blockIdx.y;
  int k = blockIdx.x * 256 + threadIdx.x;
  if (k < K)
    outp[(size_t)c * K + k] =
        (f16)((c < 128) ? Wl[(size_t)c * K + k] : Wr[(size_t)(c - 128) * K + k]);
}

__global__ void cvtW_small(const float* __restrict__ Wl_b, const float* __restrict__ Wr_b,
                           const float* __restrict__ Wl_a, const float* __restrict__ Wr_a,
                           f16* __restrict__ outp) {
  int idx = blockIdx.x * 256 + threadIdx.x;  // 4*128*256
  int l = idx >> 15;
  int c = (idx >> 8) & 127;
  int k = idx & 255;
  const float* Wl = (l < 2) ? Wl_b + (size_t)l * 16384 : Wl_a + (size_t)(l - 2) * 16384;
  const float* Wr = (l < 2) ? Wr_b + (size_t)l * 16384 : Wr_a + (size_t)(l - 2) * 16384;
  float v = (k < 128) ? Wl[(size_t)c * 128 + k] : Wr[(size_t)c * 128 + (k - 128)];
  outp[idx] = (f16)v;
}

// ---------------- CSR build ----------------
__global__ void k_count(const int* __restrict__ nbr, int* __restrict__ deg) {
  int e = blockIdx.x * 256 + threadIdx.x;
  if (e < NEDGE) atomicAdd(&deg[nbr[e]], 1);
}
__global__ void k_scan1(const int* __restrict__ deg, int* __restrict__ rowptr,
                        int* __restrict__ bsum) {
  __shared__ int s[256];
  int t = threadIdx.x, i = blockIdx.x * 256 + t;
  int v = (i < N_ATOMS) ? deg[i] : 0;
  s[t] = v;
  __syncthreads();
  for (int off = 1; off < 256; off <<= 1) {
    int x = (t >= off) ? s[t - off] : 0;
    __syncthreads();
    s[t] += x;
    __syncthreads();
  }
  if (i < N_ATOMS) rowptr[i] = s[t] - v;
  if (t == 255) bsum[blockIdx.x] = s[255];
}
__global__ void k_scan2(int* __restrict__ bsum) {
  __shared__ int s[256];
  int t = threadIdx.x;
  int v = (t < NBLK) ? bsum[t] : 0;
  s[t] = v;
  __syncthreads();
  for (int off = 1; off < 256; off <<= 1) {
    int x = (t >= off) ? s[t - off] : 0;
    __syncthreads();
    s[t] += x;
    __syncthreads();
  }
  if (t < NBLK) bsum[t] = s[t] - v;
}
__global__ void k_scan3(int* __restrict__ rowptr, const int* __restrict__ bsum) {
  int i = blockIdx.x * 256 + threadIdx.x;
  if (i < N_ATOMS) rowptr[i] += bsum[blockIdx.x];
  if (i == 0) rowptr[N_ATOMS] = NEDGE;
}
// eidx stores PRE-SCALED byte offsets (src*256): kills the per-edge 64-bit
// mul-add address chain in the gathers (base + zext(u32) addressing).
__global__ void k_fill(const int* __restrict__ nbr, const int* __restrict__ rowptr,
                       int* __restrict__ cursor, int* __restrict__ eidx) {
  int e = blockIdx.x * 256 + threadIdx.x;
  if (e < NEDGE) {
    int dst = nbr[e];
    int pos = rowptr[dst] + atomicAdd(&cursor[dst], 1);
    eidx[pos] = (e / NEIGH) << 8;  // src atom * 256 bytes (P row)
  }
}

// ---------------- layer-1 finalize: x = relu(mean_j P[src_j] + b + Q) ----------------
// 16 thr/atom; per 8-edge batch: pairwise f16x8 tree (7 vector adds = 28 pk_add)
// then one cvt+add pass into f32 acc — ~3x fewer VALU ops than scalar cvt/add.
__global__ __launch_bounds__(256) void gather_fin1(
    const f16* __restrict__ Pb, const f16* __restrict__ Qb,
    const f16* __restrict__ Pa, const f16* __restrict__ Qa,
    const int* __restrict__ rowptr, const int* __restrict__ eidx,
    const float* __restrict__ bias_b, const float* __restrict__ bias_a,
    f16* __restrict__ axb, f16* __restrict__ axa) {
  const int path = blockIdx.y;
  const char* Pc = (const char*)(path ? Pa : Pb);
  const f16* Q = path ? Qa : Qb;
  const float* bias = path ? bias_a : bias_b;
  f16* ax = path ? axa : axb;
  const int t = threadIdx.x;
  const int a = blockIdx.x * 16 + (t >> 4);
  const int g = (t & 15) * 8;
  const unsigned gb = (unsigned)(t & 15) * 16;  // byte offset within row
  const int s0 = rowptr[a], s1 = rowptr[a + 1];
  float acc[8];
#pragma unroll
  for (int u = 0; u < 8; ++u) acc[u] = 0.f;
  int j = s0;
  for (; j + 8 <= s1; j += 8) {
    f16x8 v[8];
#pragma unroll
    for (int u = 0; u < 8; ++u)
      v[u] = *(const f16x8*)(Pc + (size_t)((unsigned)eidx[j + u] + gb));
    f16x8 s = ((v[0] + v[1]) + (v[2] + v[3])) + ((v[4] + v[5]) + (v[6] + v[7]));
#pragma unroll
    for (int c = 0; c < 8; ++c) acc[c] += (float)s[c];
  }
  for (; j + 4 <= s1; j += 4) {
    f16x8 v0 = *(const f16x8*)(Pc + (size_t)((unsigned)eidx[j] + gb));
    f16x8 v1 = *(const f16x8*)(Pc + (size_t)((unsigned)eidx[j + 1] + gb));
    f16x8 v2 = *(const f16x8*)(Pc + (size_t)((unsigned)eidx[j + 2] + gb));
    f16x8 v3 = *(const f16x8*)(Pc + (size_t)((unsigned)eidx[j + 3] + gb));
    f16x8 s = (v0 + v1) + (v2 + v3);
#pragma unroll
    for (int c = 0; c < 8; ++c) acc[c] += (float)s[c];
  }
  for (; j < s1; ++j) {
    f16x8 v = *(const f16x8*)(Pc + (size_t)((unsigned)eidx[j] + gb));
#pragma unroll
    for (int c = 0; c < 8; ++c) acc[c] += (float)v[c];
  }
  f16x8 q = *(const f16x8*)&Q[(size_t)a * 128 + g];
  float inv = 1.0f / fmaxf((float)(s1 - s0), 1.0f);
  f16 outv[8];
#pragma unroll
  for (int u = 0; u < 8; ++u) {
    float v = acc[u] * inv + bias[g + u] + (float)q[u];
    outv[u] = (f16)fmaxf(v, 0.0f);
  }
  *(f16x8*)&ax[(size_t)a * 256 + 128 + g] = *(const f16x8*)outv;
}

// ---------------- layers 2-3 aggregation: agg half <- mean_j x[src_j] ----------------
// x-half rows live at ax + src*512B + 256B: off512 = eidx<<1 (+256 +lane byte).
__global__ __launch_bounds__(256) void gather_mean(
    f16* __restrict__ axb, f16* __restrict__ axa,
    const int* __restrict__ rowptr, const int* __restrict__ eidx) {
  f16* ax = blockIdx.y ? axa : axb;
  const char* axc = (const char*)ax;
  const int t = threadIdx.x;
  const int a = blockIdx.x * 16 + (t >> 4);
  const int g = (t & 15) * 8;
  const unsigned gb = 256u + (unsigned)(t & 15) * 16;
  const int s0 = rowptr[a], s1 = rowptr[a + 1];
  float acc[8];
#pragma unroll
  for (int u = 0; u < 8; ++u) acc[u] = 0.f;
  int j = s0;
  for (; j + 8 <= s1; j += 8) {
    f16x8 v[8];
#pragma unroll
    for (int u = 0; u < 8; ++u)
      v[u] = *(const f16x8*)(axc + (size_t)(((unsigned)eidx[j + u] << 1) + gb));
    f16x8 s = ((v[0] + v[1]) + (v[2] + v[3])) + ((v[4] + v[5]) + (v[6] + v[7]));
#pragma unroll
    for (int c = 0; c < 8; ++c) acc[c] += (float)s[c];
  }
  for (; j + 4 <= s1; j += 4) {
    f16x8 v0 = *(const f16x8*)(axc + (size_t)(((unsigned)eidx[j] << 1) + gb));
    f16x8 v1 = *(const f16x8*)(axc + (size_t)(((unsigned)eidx[j + 1] << 1) + gb));
    f16x8 v2 = *(const f16x8*)(axc + (size_t)(((unsigned)eidx[j + 2] << 1) + gb));
    f16x8 v3 = *(const f16x8*)(axc + (size_t)(((unsigned)eidx[j + 3] << 1) + gb));
    f16x8 s = (v0 + v1) + (v2 + v3);
#pragma unroll
    for (int c = 0; c < 8; ++c) acc[c] += (float)s[c];
  }
  for (; j < s1; ++j) {
    f16x8 v = *(const f16x8*)(axc + (size_t)(((unsigned)eidx[j] << 1) + gb));
#pragma unroll
    for (int c = 0; c < 8; ++c) acc[c] += (float)v[c];
  }
  float inv = 1.0f / fmaxf((float)(s1 - s0), 1.0f);
  f16 outv[8];
#pragma unroll
  for (int u = 0; u < 8; ++u) outv[u] = (f16)(acc[u] * inv);
  *(f16x8*)&ax[(size_t)a * 256 + g] = *(const f16x8*)outv;
}

// ---------------- head: pool -> mlp -> mlp -> fc ----------------
__global__ __launch_bounds__(256) void head_kernel(
    const f16* __restrict__ axb, const f16* __restrict__ axa,
    const int* __restrict__ crys, const float* __restrict__ W_mlp,
    const float* __restrict__ b_mlp, const float* __restrict__ W_fc,
    const float* __restrict__ b_fc, float* __restrict__ outp) {
  __shared__ float sh0[256], sh1[256];
  const int cry = blockIdx.x, c = threadIdx.x;
  const int s = crys[2 * cry], e = crys[2 * cry + 1];
  const f16* src = (c < 128) ? axb : axa;
  const int ch = c & 127;
  float sum = 0.f;
  for (int r = s; r < e; ++r) sum += (float)src[(size_t)r * 256 + 128 + ch];
  sh0[c] = sum / fmaxf((float)(e - s), 1.0f);
  __syncthreads();
  {
    const float* wrow = W_mlp + (size_t)c * 256;
    float s2 = b_mlp[c];
#pragma unroll 8
    for (int k = 0; k < 256; k += 4) {
      float4 w = *(const float4*)&wrow[k];
      s2 += sh0[k] * w.x + sh0[k + 1] * w.y + sh0[k + 2] * w.z + sh0[k + 3] * w.w;
    }
    sh1[c] = s2;
  }
  __syncthreads();
  {
    const float* wrow = W_mlp + 65536 + (size_t)c * 256;
    float s2 = b_mlp[256 + c];
#pragma unroll 8
    for (int k = 0; k < 256; k += 4) {
      float4 w = *(const float4*)&wrow[k];
      s2 += sh1[k] * w.x + sh1[k + 1] * w.y + sh1[k + 2] * w.z + sh1[k + 3] * w.w;
    }
    sh0[c] = s2;
  }
  __syncthreads();
  if (c < 2) {
    const float* wrow = W_fc + c * 256;
    float s2 = b_fc[c];
    for (int k = 0; k < 256; ++k) s2 += sh0[k] * wrow[k];
    outp[cry * 2 + c] = s2;
  }
}

extern "C" void kernel_launch(void* const* d_in, const int* in_sizes, int n_in,
                              void* d_out, int out_size, void* d_ws, size_t ws_size,
                              hipStream_t stream) {
  const float* bond  = (const float*)d_in[0];
  const float* angle = (const float*)d_in[1];
  const int*   nbr   = (const int*)d_in[3];
  const int*   crys  = (const int*)d_in[4];
  const float* Wl_b1 = (const float*)d_in[5];
  const float* Wr_b1 = (const float*)d_in[6];
  const float* b_b1  = (const float*)d_in[7];
  const float* Wl_a1 = (const float*)d_in[8];
  const float* Wr_a1 = (const float*)d_in[9];
  const float* b_a1  = (const float*)d_in[10];
  const float* Wl_b  = (const float*)d_in[11];
  const float* Wr_b  = (const float*)d_in[12];
  const float* b_b   = (const float*)d_in[13];
  const float* Wl_a  = (const float*)d_in[14];
  const float* Wr_a  = (const float*)d_in[15];
  const float* b_a   = (const float*)d_in[16];
  const float* W_mlp = (const float*)d_in[17];
  const float* b_mlp = (const float*)d_in[18];
  const float* W_fc  = (const float*)d_in[19];
  const float* b_fc  = (const float*)d_in[20];

  char* w = (char*)d_ws;
  auto alloc = [&](size_t bytes) {
    void* p = (void*)w;
    w += (bytes + 255) & ~(size_t)255;
    return p;
  };
  // ping-pong activation buffers; layer-1 P/Q alias the B buffers
  f16* axbA = (f16*)alloc((size_t)N_ATOMS * 256 * 2);
  f16* axaA = (f16*)alloc((size_t)N_ATOMS * 256 * 2);
  f16* axbB = (f16*)alloc((size_t)N_ATOMS * 256 * 2);
  f16* axaB = (f16*)alloc((size_t)N_ATOMS * 256 * 2);
  f16* Pb = axbB;
  f16* Qb = axbB + (size_t)N_ATOMS * 128;
  f16* Pa = axaB;
  f16* Qa = axaB + (size_t)N_ATOMS * 128;
  f16* Wb1c = (f16*)alloc((size_t)256 * 480 * 2);
  f16* Wa1c = (f16*)alloc((size_t)256 * 1152 * 2);
  f16* Wsm  = (f16*)alloc((size_t)4 * 128 * 256 * 2);
  // deg+cursor as ONE contiguous block: the single memset must cover BOTH
  // (0xAA re-poison between timed replays otherwise leaves cursor garbage).
  int* deg    = (int*)alloc((size_t)2 * N_ATOMS * 4);
  int* cursor = deg + N_ATOMS;
  int* rowptr = (int*)alloc((size_t)(N_ATOMS + 1) * 4);
  int* eidx   = (int*)alloc((size_t)NEDGE * 4);
  int* bsum   = (int*)alloc(256 * 4);

  // weights -> fp16
  cvtW<<<dim3(2, 256), 256, 0, stream>>>(Wl_b1, Wr_b1, Wb1c, 480);
  cvtW<<<dim3(5, 256), 256, 0, stream>>>(Wl_a1, Wr_a1, Wa1c, 1152);
  cvtW_small<<<512, 256, 0, stream>>>(Wl_b, Wr_b, Wl_a, Wr_a, Wsm);

  // CSR build
  hipMemsetAsync(deg, 0, (size_t)2 * N_ATOMS * 4, stream);
  k_count<<<(NEDGE + 255) / 256, 256, 0, stream>>>(nbr, deg);
  k_scan1<<<NBLK, 256, 0, stream>>>(deg, rowptr, bsum);
  k_scan2<<<1, 256, 0, stream>>>(bsum);
  k_scan3<<<NBLK, 256, 0, stream>>>(rowptr, bsum);
  k_fill<<<(NEDGE + 255) / 256, 256, 0, stream>>>(nbr, rowptr, cursor, eidx);

  const int GT = (N_ATOMS + 255) / 256;  // 196 (gemm1, BM=256)
  const int GG = (N_ATOMS + 127) / 128;  // 391 (gemmL, BM=128)
  const int AG = N_ATOMS / 16;           // 3125

  // layer 1 (R6 form: GBF fused in A-stage, N-split over y; project-then-aggregate)
  gemm1<2, 1152><<<dim3(GT, 2), 512, 0, stream>>>(angle, Wa1c, Pa, Qa, N_ATOMS);
  gemm1<1, 480><<<dim3(GT, 2), 512, 0, stream>>>(bond, Wb1c, Pb, Qb, N_ATOMS);
  gather_fin1<<<dim3(AG, 2), 256, 0, stream>>>(Pb, Qb, Pa, Qa, rowptr, eidx,
                                               b_b1, b_a1, axbA, axaA);

  // layers 2-3 (aggregate-then-project, ping-pong A -> B -> A)
  gather_mean<<<dim3(AG, 2), 256, 0, stream>>>(axbA, axaA, rowptr, eidx);
  gemmL_reg<<<dim3(GG, 2), 256, 0, stream>>>(axbA, axaA, axbB, axaB, Wsm, b_b, b_a,
                                             0, N_ATOMS);
  gather_mean<<<dim3(AG, 2), 256, 0, stream>>>(axbB, axaB, rowptr, eidx);
  gemmL_reg<<<dim3(GG, 2), 256, 0, stream>>>(axbB, axaB, axbA, axaA, Wsm, b_b, b_a,
                                             1, N_ATOMS);

  // head
  head_kernel<<<NCRYS, 256, 0, stream>>>(axbA, axaA, crys, W_mlp, b_mlp, W_fc, b_fc,
                                         (float*)d_out);
}

// Round 12
// 405.371 us; speedup vs baseline: 1.1440x; 1.0915x over previous
//
#include <hip/hip_runtime.h>

typedef _Float16 f16;
typedef _Float16 f16x8 __attribute__((ext_vector_type(8)));
typedef float f32x4 __attribute__((ext_vector_type(4)));

#define N_ATOMS 50000
#define NEIGH   12
#define NEDGE   (N_ATOMS * NEIGH)
#define NCRYS   500
#define NBLK    196  // ceil(50000/256)

__device__ __forceinline__ void gld_lds16(const void* g, void* l) {
  __builtin_amdgcn_global_load_lds(
      (const __attribute__((address_space(1))) unsigned int*)g,
      (__attribute__((address_space(3))) unsigned int*)l, 16, 0, 0);
}

typedef f16 AsT[2][4][256][8];  // 32 KB
typedef f16 BsT[2][4][128][8];  // 16 KB

// ---------------- layer-1 GEMM body (R6 form — measured best) ----------------
// BM=256 rows/block, BN=128 cols; half: 0 -> Wl (P), 1 -> Wr (Q).
// LDS passed in so the two template instantiations share one 48 KB allocation.
template <int MODE, int K>
__device__ __forceinline__ void gemm1_body(
    const float* __restrict__ Asrc, const f16* __restrict__ Wcat,
    f16* __restrict__ P, f16* __restrict__ Q, int n, AsT& As, BsT& Bs) {
  const int tid = threadIdx.x;
  const int lane = tid & 63;
  const int wid = tid >> 6;
  const int wr = wid >> 1;  // 0..3 (64-row strip)
  const int wc = wid & 1;   // 0..1 (64-col strip)
  const int row0 = blockIdx.x * 256;
  const int half = blockIdx.y;
  const f16* Wh = Wcat + (size_t)half * 128 * K;
  f16* outp = half ? Q : P;

  const int bcol = tid & 127;
  const int bkb = tid >> 7;  // 0..3
  const int sArow = tid & 255;
  const int sAkb0 = tid >> 8;  // 0..1 (+2 on pass 1)
  int arow = row0 + sArow;
  if (arow >= n) arow = n - 1;

  f32x4 acc[4][4];
#pragma unroll
  for (int m = 0; m < 4; ++m)
#pragma unroll
    for (int q = 0; q < 4; ++q) acc[m][q] = (f32x4)0.f;

  auto stage = [&](int buf, int k0) {
    gld_lds16(Wh + (size_t)bcol * K + k0 + bkb * 8, &Bs[buf][bkb][bcol][0]);
#pragma unroll
    for (int p = 0; p < 2; ++p) {
      int kb = sAkb0 + 2 * p;
      int kg0 = k0 + kb * 8;
      f16 v[8];
      if constexpr (MODE == 1) {
        int jn = kg0 / 40;  // 40 % 8 == 0: 8-block never crosses a filter group
        int kk0 = kg0 - jn * 40;
        float d = Asrc[arow * NEIGH + jn];
#pragma unroll
        for (int j = 0; j < 8; ++j) {
          float t = d - (kk0 + j) * (8.0f / 39.0f);
          v[j] = (f16)__expf(-t * t * 25.0f);  // gamma = 8/40
        }
      } else {
        int jn = kg0 >> 3;
        float d = Asrc[arow * 144 + jn];
#pragma unroll
        for (int j = 0; j < 8; ++j) {
          float t = d - (-1.0f + j * (2.0f / 7.0f));
          v[j] = (f16)__expf(-t * t * 16.0f);  // gamma = 2/8
        }
      }
      *(f16x8*)&As[buf][kb][sArow][0] = *(const f16x8*)v;
    }
  };

  constexpr int NT = K / 32;
  stage(0, 0);
  __syncthreads();
  int buf = 0;
  for (int t = 0; t < NT; ++t) {
    if (t + 1 < NT) stage(buf ^ 1, (t + 1) * 32);
    const int kb = lane >> 4;
    const int r16 = lane & 15;
    f16x8 a[4], b[4];
#pragma unroll
    for (int m = 0; m < 4; ++m)
      a[m] = *(const f16x8*)&As[buf][kb][wr * 64 + m * 16 + r16][0];
#pragma unroll
    for (int q = 0; q < 4; ++q)
      b[q] = *(const f16x8*)&Bs[buf][kb][wc * 64 + q * 16 + r16][0];
#pragma unroll
    for (int m = 0; m < 4; ++m)
#pragma unroll
      for (int q = 0; q < 4; ++q)
        acc[m][q] =
            __builtin_amdgcn_mfma_f32_16x16x32_f16(a[m], b[q], acc[m][q], 0, 0, 0);
    __syncthreads();
    buf ^= 1;
  }

  const int crow = (lane >> 4) * 4;
  const int ccol = lane & 15;
#pragma unroll
  for (int m = 0; m < 4; ++m) {
#pragma unroll
    for (int r = 0; r < 4; ++r) {
      int row = row0 + wr * 64 + m * 16 + crow + r;
      if (row < n) {
#pragma unroll
        for (int q = 0; q < 4; ++q)
          outp[(size_t)row * 128 + wc * 64 + q * 16 + ccol] = (f16)acc[m][q][r];
      }
    }
  }
}

// grid (196, 2, 2): y = W-half, z = mode (0 angle K=1152, 1 bond K=480).
// One dispatch -> bond blocks co-resident with angle blocks (fill latency gaps).
__global__ __launch_bounds__(512) void gemm1all(
    const float* __restrict__ angle, const f16* __restrict__ Wa,
    f16* __restrict__ Pa, f16* __restrict__ Qa,
    const float* __restrict__ bond, const f16* __restrict__ Wb,
    f16* __restrict__ Pb, f16* __restrict__ Qb, int n) {
  __shared__ __align__(16) AsT As;
  __shared__ __align__(16) BsT Bs;
  if (blockIdx.z == 0)
    gemm1_body<2, 1152>(angle, Wa, Pa, Qa, n, As, Bs);
  else
    gemm1_body<1, 480>(bond, Wb, Pb, Qb, n, As, Bs);
}

// ---------------- layers 2-3 (R6 LDS form): x' = relu([agg|x] @ Wcat2^T + b) ----
// BM=256, BN=128, 512 threads. axcat [N][256]: 0-127 agg, 128-255 x (IN-PLACE:
// within a block all A-reads precede the epilogue writes; rows disjoint across
// blocks -> safe; verified passing in R6). blockIdx.y = path.
__global__ __launch_bounds__(512) void gemmL(
    f16* __restrict__ axb, f16* __restrict__ axa, const f16* __restrict__ Wall,
    const float* __restrict__ bb, const float* __restrict__ ba, int lidx, int n) {
  __shared__ __align__(16) AsT As;
  __shared__ __align__(16) BsT Bs;
  const int path = blockIdx.y;
  f16* ax = path ? axa : axb;
  const f16* W = Wall + (size_t)(path * 2 + lidx) * 32768;
  const float* bias = (path ? ba : bb) + lidx * 128;

  const int tid = threadIdx.x;
  const int lane = tid & 63;
  const int wid = tid >> 6;
  const int wr = wid >> 1;  // 0..3
  const int wc = wid & 1;   // 0..1
  const int row0 = blockIdx.x * 256;

  const int bcol = tid & 127;
  const int bkb = tid >> 7;  // 0..3
  const int sArow = tid & 255;
  const int sAkb0 = tid >> 8;  // 0..1
  int arow = row0 + sArow;
  if (arow >= n) arow = n - 1;

  f32x4 acc[4][4];
#pragma unroll
  for (int m = 0; m < 4; ++m)
#pragma unroll
    for (int q = 0; q < 4; ++q) acc[m][q] = (f32x4)0.f;

  auto stage = [&](int buf, int k0) {
    gld_lds16(W + (size_t)bcol * 256 + k0 + bkb * 8, &Bs[buf][bkb][bcol][0]);
#pragma unroll
    for (int p = 0; p < 2; ++p) {
      int kb = sAkb0 + 2 * p;
      gld_lds16(ax + (size_t)arow * 256 + k0 + kb * 8, &As[buf][kb][sArow][0]);
    }
  };

  stage(0, 0);
  __syncthreads();
  int buf = 0;
  for (int t = 0; t < 8; ++t) {
    if (t + 1 < 8) stage(buf ^ 1, (t + 1) * 32);
    const int kb = lane >> 4;
    const int r16 = lane & 15;
    f16x8 a[4], b[4];
#pragma unroll
    for (int m = 0; m < 4; ++m)
      a[m] = *(const f16x8*)&As[buf][kb][wr * 64 + m * 16 + r16][0];
#pragma unroll
    for (int q = 0; q < 4; ++q)
      b[q] = *(const f16x8*)&Bs[buf][kb][wc * 64 + q * 16 + r16][0];
#pragma unroll
    for (int m = 0; m < 4; ++m)
#pragma unroll
      for (int q = 0; q < 4; ++q)
        acc[m][q] =
            __builtin_amdgcn_mfma_f32_16x16x32_f16(a[m], b[q], acc[m][q], 0, 0, 0);
    __syncthreads();
    buf ^= 1;
  }

  const int crow = (lane >> 4) * 4;
  const int ccol = lane & 15;
#pragma unroll
  for (int m = 0; m < 4; ++m) {
#pragma unroll
    for (int r = 0; r < 4; ++r) {
      int row = row0 + wr * 64 + m * 16 + crow + r;
      if (row < n) {
#pragma unroll
        for (int q = 0; q < 4; ++q) {
          int col = wc * 64 + q * 16 + ccol;
          float v = acc[m][q][r] + bias[col];
          ax[(size_t)row * 256 + 128 + col] = (f16)fmaxf(v, 0.0f);
        }
      }
    }
  }
}

// ---------------- weight conversion ----------------
__global__ void cvtW(const float* __restrict__ Wl, const float* __restrict__ Wr,
                     f16* __restrict__ outp, int K) {
  int c = blockIdx.y;
  int k = blockIdx.x * 256 + threadIdx.x;
  if (k < K)
    outp[(size_t)c * K + k] =
        (f16)((c < 128) ? Wl[(size_t)c * K + k] : Wr[(size_t)(c - 128) * K + k]);
}

__global__ void cvtW_small(const float* __restrict__ Wl_b, const float* __restrict__ Wr_b,
                           const float* __restrict__ Wl_a, const float* __restrict__ Wr_a,
                           f16* __restrict__ outp) {
  int idx = blockIdx.x * 256 + threadIdx.x;  // 4*128*256
  int l = idx >> 15;
  int c = (idx >> 8) & 127;
  int k = idx & 255;
  const float* Wl = (l < 2) ? Wl_b + (size_t)l * 16384 : Wl_a + (size_t)(l - 2) * 16384;
  const float* Wr = (l < 2) ? Wr_b + (size_t)l * 16384 : Wr_a + (size_t)(l - 2) * 16384;
  float v = (k < 128) ? Wl[(size_t)c * 128 + k] : Wr[(size_t)c * 128 + (k - 128)];
  outp[idx] = (f16)v;
}

// ---------------- CSR build ----------------
__global__ void k_count(const int* __restrict__ nbr, int* __restrict__ deg) {
  int e = blockIdx.x * 256 + threadIdx.x;
  if (e < NEDGE) atomicAdd(&deg[nbr[e]], 1);
}
__global__ void k_scan1(const int* __restrict__ deg, int* __restrict__ rowptr,
                        int* __restrict__ bsum) {
  __shared__ int s[256];
  int t = threadIdx.x, i = blockIdx.x * 256 + t;
  int v = (i < N_ATOMS) ? deg[i] : 0;
  s[t] = v;
  __syncthreads();
  for (int off = 1; off < 256; off <<= 1) {
    int x = (t >= off) ? s[t - off] : 0;
    __syncthreads();
    s[t] += x;
    __syncthreads();
  }
  if (i < N_ATOMS) rowptr[i] = s[t] - v;
  if (t == 255) bsum[blockIdx.x] = s[255];
}
__global__ void k_scan2(int* __restrict__ bsum) {
  __shared__ int s[256];
  int t = threadIdx.x;
  int v = (t < NBLK) ? bsum[t] : 0;
  s[t] = v;
  __syncthreads();
  for (int off = 1; off < 256; off <<= 1) {
    int x = (t >= off) ? s[t - off] : 0;
    __syncthreads();
    s[t] += x;
    __syncthreads();
  }
  if (t < NBLK) bsum[t] = s[t] - v;
}
__global__ void k_scan3(int* __restrict__ rowptr, const int* __restrict__ bsum) {
  int i = blockIdx.x * 256 + threadIdx.x;
  if (i < N_ATOMS) rowptr[i] += bsum[blockIdx.x];
  if (i == 0) rowptr[N_ATOMS] = NEDGE;
}
// eidx stores PRE-SCALED byte offsets (src*256) for base+zext(u32) addressing.
__global__ void k_fill(const int* __restrict__ nbr, const int* __restrict__ rowptr,
                       int* __restrict__ cursor, int* __restrict__ eidx) {
  int e = blockIdx.x * 256 + threadIdx.x;
  if (e < NEDGE) {
    int dst = nbr[e];
    int pos = rowptr[dst] + atomicAdd(&cursor[dst], 1);
    eidx[pos] = (e / NEIGH) << 8;  // src atom * 256 bytes (P row)
  }
}

// ---------------- layer-1 finalize: x = relu(mean_j P[src_j] + b + Q) ----------------
__global__ __launch_bounds__(256) void gather_fin1(
    const f16* __restrict__ Pb, const f16* __restrict__ Qb,
    const f16* __restrict__ Pa, const f16* __restrict__ Qa,
    const int* __restrict__ rowptr, const int* __restrict__ eidx,
    const float* __restrict__ bias_b, const float* __restrict__ bias_a,
    f16* __restrict__ axb, f16* __restrict__ axa) {
  const int path = blockIdx.y;
  const char* Pc = (const char*)(path ? Pa : Pb);
  const f16* Q = path ? Qa : Qb;
  const float* bias = path ? bias_a : bias_b;
  f16* ax = path ? axa : axb;
  const int t = threadIdx.x;
  const int a = blockIdx.x * 16 + (t >> 4);
  const int g = (t & 15) * 8;
  const unsigned gb = (unsigned)(t & 15) * 16;
  const int s0 = rowptr[a], s1 = rowptr[a + 1];
  float acc[8];
#pragma unroll
  for (int u = 0; u < 8; ++u) acc[u] = 0.f;
  int j = s0;
  for (; j + 8 <= s1; j += 8) {
    f16x8 v[8];
#pragma unroll
    for (int u = 0; u < 8; ++u)
      v[u] = *(const f16x8*)(Pc + (size_t)((unsigned)eidx[j + u] + gb));
    f16x8 s = ((v[0] + v[1]) + (v[2] + v[3])) + ((v[4] + v[5]) + (v[6] + v[7]));
#pragma unroll
    for (int c = 0; c < 8; ++c) acc[c] += (float)s[c];
  }
  for (; j + 4 <= s1; j += 4) {
    f16x8 v0 = *(const f16x8*)(Pc + (size_t)((unsigned)eidx[j] + gb));
    f16x8 v1 = *(const f16x8*)(Pc + (size_t)((unsigned)eidx[j + 1] + gb));
    f16x8 v2 = *(const f16x8*)(Pc + (size_t)((unsigned)eidx[j + 2] + gb));
    f16x8 v3 = *(const f16x8*)(Pc + (size_t)((unsigned)eidx[j + 3] + gb));
    f16x8 s = (v0 + v1) + (v2 + v3);
#pragma unroll
    for (int c = 0; c < 8; ++c) acc[c] += (float)s[c];
  }
  for (; j < s1; ++j) {
    f16x8 v = *(const f16x8*)(Pc + (size_t)((unsigned)eidx[j] + gb));
#pragma unroll
    for (int c = 0; c < 8; ++c) acc[c] += (float)v[c];
  }
  f16x8 q = *(const f16x8*)&Q[(size_t)a * 128 + g];
  float inv = 1.0f / fmaxf((float)(s1 - s0), 1.0f);
  f16 outv[8];
#pragma unroll
  for (int u = 0; u < 8; ++u) {
    float v = acc[u] * inv + bias[g + u] + (float)q[u];
    outv[u] = (f16)fmaxf(v, 0.0f);
  }
  *(f16x8*)&ax[(size_t)a * 256 + 128 + g] = *(const f16x8*)outv;
}

// ---------------- layers 2-3 aggregation: agg half <- mean_j x[src_j] ----------------
__global__ __launch_bounds__(256) void gather_mean(
    f16* __restrict__ axb, f16* __restrict__ axa,
    const int* __restrict__ rowptr, const int* __restrict__ eidx) {
  f16* ax = blockIdx.y ? axa : axb;
  const char* axc = (const char*)ax;
  const int t = threadIdx.x;
  const int a = blockIdx.x * 16 + (t >> 4);
  const int g = (t & 15) * 8;
  const unsigned gb = 256u + (unsigned)(t & 15) * 16;
  const int s0 = rowptr[a], s1 = rowptr[a + 1];
  float acc[8];
#pragma unroll
  for (int u = 0; u < 8; ++u) acc[u] = 0.f;
  int j = s0;
  for (; j + 8 <= s1; j += 8) {
    f16x8 v[8];
#pragma unroll
    for (int u = 0; u < 8; ++u)
      v[u] = *(const f16x8*)(axc + (size_t)(((unsigned)eidx[j + u] << 1) + gb));
    f16x8 s = ((v[0] + v[1]) + (v[2] + v[3])) + ((v[4] + v[5]) + (v[6] + v[7]));
#pragma unroll
    for (int c = 0; c < 8; ++c) acc[c] += (float)s[c];
  }
  for (; j + 4 <= s1; j += 4) {
    f16x8 v0 = *(const f16x8*)(axc + (size_t)(((unsigned)eidx[j] << 1) + gb));
    f16x8 v1 = *(const f16x8*)(axc + (size_t)(((unsigned)eidx[j + 1] << 1) + gb));
    f16x8 v2 = *(const f16x8*)(axc + (size_t)(((unsigned)eidx[j + 2] << 1) + gb));
    f16x8 v3 = *(const f16x8*)(axc + (size_t)(((unsigned)eidx[j + 3] << 1) + gb));
    f16x8 s = (v0 + v1) + (v2 + v3);
#pragma unroll
    for (int c = 0; c < 8; ++c) acc[c] += (float)s[c];
  }
  for (; j < s1; ++j) {
    f16x8 v = *(const f16x8*)(axc + (size_t)(((unsigned)eidx[j] << 1) + gb));
#pragma unroll
    for (int c = 0; c < 8; ++c) acc[c] += (float)v[c];
  }
  float inv = 1.0f / fmaxf((float)(s1 - s0), 1.0f);
  f16 outv[8];
#pragma unroll
  for (int u = 0; u < 8; ++u) outv[u] = (f16)(acc[u] * inv);
  *(f16x8*)&ax[(size_t)a * 256 + g] = *(const f16x8*)outv;
}

// ---------------- head: pool -> mlp -> mlp -> fc ----------------
__global__ __launch_bounds__(256) void head_kernel(
    const f16* __restrict__ axb, const f16* __restrict__ axa,
    const int* __restrict__ crys, const float* __restrict__ W_mlp,
    const float* __restrict__ b_mlp, const float* __restrict__ W_fc,
    const float* __restrict__ b_fc, float* __restrict__ outp) {
  __shared__ float sh0[256], sh1[256];
  const int cry = blockIdx.x, c = threadIdx.x;
  const int s = crys[2 * cry], e = crys[2 * cry + 1];
  const f16* src = (c < 128) ? axb : axa;
  const int ch = c & 127;
  float sum = 0.f;
  for (int r = s; r < e; ++r) sum += (float)src[(size_t)r * 256 + 128 + ch];
  sh0[c] = sum / fmaxf((float)(e - s), 1.0f);
  __syncthreads();
  {
    const float* wrow = W_mlp + (size_t)c * 256;
    float s2 = b_mlp[c];
#pragma unroll 8
    for (int k = 0; k < 256; k += 4) {
      float4 w = *(const float4*)&wrow[k];
      s2 += sh0[k] * w.x + sh0[k + 1] * w.y + sh0[k + 2] * w.z + sh0[k + 3] * w.w;
    }
    sh1[c] = s2;
  }
  __syncthreads();
  {
    const float* wrow = W_mlp + 65536 + (size_t)c * 256;
    float s2 = b_mlp[256 + c];
#pragma unroll 8
    for (int k = 0; k < 256; k += 4) {
      float4 w = *(const float4*)&wrow[k];
      s2 += sh1[k] * w.x + sh1[k + 1] * w.y + sh1[k + 2] * w.z + sh1[k + 3] * w.w;
    }
    sh0[c] = s2;
  }
  __syncthreads();
  if (c < 2) {
    const float* wrow = W_fc + c * 256;
    float s2 = b_fc[c];
    for (int k = 0; k < 256; ++k) s2 += sh0[k] * wrow[k];
    outp[cry * 2 + c] = s2;
  }
}

extern "C" void kernel_launch(void* const* d_in, const int* in_sizes, int n_in,
                              void* d_out, int out_size, void* d_ws, size_t ws_size,
                              hipStream_t stream) {
  const float* bond  = (const float*)d_in[0];
  const float* angle = (const float*)d_in[1];
  const int*   nbr   = (const int*)d_in[3];
  const int*   crys  = (const int*)d_in[4];
  const float* Wl_b1 = (const float*)d_in[5];
  const float* Wr_b1 = (const float*)d_in[6];
  const float* b_b1  = (const float*)d_in[7];
  const float* Wl_a1 = (const float*)d_in[8];
  const float* Wr_a1 = (const float*)d_in[9];
  const float* b_a1  = (const float*)d_in[10];
  const float* Wl_b  = (const float*)d_in[11];
  const float* Wr_b  = (const float*)d_in[12];
  const float* b_b   = (const float*)d_in[13];
  const float* Wl_a  = (const float*)d_in[14];
  const float* Wr_a  = (const float*)d_in[15];
  const float* b_a   = (const float*)d_in[16];
  const float* W_mlp = (const float*)d_in[17];
  const float* b_mlp = (const float*)d_in[18];
  const float* W_fc  = (const float*)d_in[19];
  const float* b_fc  = (const float*)d_in[20];

  char* w = (char*)d_ws;
  auto alloc = [&](size_t bytes) {
    void* p = (void*)w;
    w += (bytes + 255) & ~(size_t)255;
    return p;
  };
  f16* axb = (f16*)alloc((size_t)N_ATOMS * 256 * 2);
  f16* axa = (f16*)alloc((size_t)N_ATOMS * 256 * 2);
  f16* Pb  = (f16*)alloc((size_t)N_ATOMS * 128 * 2);
  f16* Qb  = (f16*)alloc((size_t)N_ATOMS * 128 * 2);
  f16* Pa  = (f16*)alloc((size_t)N_ATOMS * 128 * 2);
  f16* Qa  = (f16*)alloc((size_t)N_ATOMS * 128 * 2);
  f16* Wb1c = (f16*)alloc((size_t)256 * 480 * 2);
  f16* Wa1c = (f16*)alloc((size_t)256 * 1152 * 2);
  f16* Wsm  = (f16*)alloc((size_t)4 * 128 * 256 * 2);
  // deg+cursor as ONE contiguous block: the single memset must cover BOTH
  // (0xAA re-poison between timed replays otherwise leaves cursor garbage).
  int* deg    = (int*)alloc((size_t)2 * N_ATOMS * 4);
  int* cursor = deg + N_ATOMS;
  int* rowptr = (int*)alloc((size_t)(N_ATOMS + 1) * 4);
  int* eidx   = (int*)alloc((size_t)NEDGE * 4);
  int* bsum   = (int*)alloc(256 * 4);

  // weights -> fp16
  cvtW<<<dim3(2, 256), 256, 0, stream>>>(Wl_b1, Wr_b1, Wb1c, 480);
  cvtW<<<dim3(5, 256), 256, 0, stream>>>(Wl_a1, Wr_a1, Wa1c, 1152);
  cvtW_small<<<512, 256, 0, stream>>>(Wl_b, Wr_b, Wl_a, Wr_a, Wsm);

  // CSR build
  hipMemsetAsync(deg, 0, (size_t)2 * N_ATOMS * 4, stream);
  k_count<<<(NEDGE + 255) / 256, 256, 0, stream>>>(nbr, deg);
  k_scan1<<<NBLK, 256, 0, stream>>>(deg, rowptr, bsum);
  k_scan2<<<1, 256, 0, stream>>>(bsum);
  k_scan3<<<NBLK, 256, 0, stream>>>(rowptr, bsum);
  k_fill<<<(NEDGE + 255) / 256, 256, 0, stream>>>(nbr, rowptr, cursor, eidx);

  const int GT = (N_ATOMS + 255) / 256;  // 196
  const int AG = N_ATOMS / 16;           // 3125

  // layer 1: single dispatch covers angle+bond x both W-halves
  gemm1all<<<dim3(GT, 2, 2), 512, 0, stream>>>(angle, Wa1c, Pa, Qa,
                                               bond, Wb1c, Pb, Qb, N_ATOMS);
  gather_fin1<<<dim3(AG, 2), 256, 0, stream>>>(Pb, Qb, Pa, Qa, rowptr, eidx,
                                               b_b1, b_a1, axb, axa);

  // layers 2-3 (aggregate-then-project, in-place ax)
  for (int l = 0; l < 2; ++l) {
    gather_mean<<<dim3(AG, 2), 256, 0, stream>>>(axb, axa, rowptr, eidx);
    gemmL<<<dim3(GT, 2), 512, 0, stream>>>(axb, axa, Wsm, b_b, b_a, l, N_ATOMS);
  }

  // head
  head_kernel<<<NCRYS, 256, 0, stream>>>(axb, axa, crys, W_mlp, b_mlp, W_fc, b_fc,
                                         (float*)d_out);
}

// Round 13
// 403.899 us; speedup vs baseline: 1.1482x; 1.0036x over previous
//
#include <hip/hip_runtime.h>

typedef _Float16 f16;
typedef _Float16 f16x8 __attribute__((ext_vector_type(8)));
typedef float f32x4 __attribute__((ext_vector_type(4)));

#define N_ATOMS 50000
#define NEIGH   12
#define NEDGE   (N_ATOMS * NEIGH)
#define NCRYS   500
#define NBLK    196  // ceil(50000/256)

__device__ __forceinline__ void gld_lds16(const void* g, void* l) {
  __builtin_amdgcn_global_load_lds(
      (const __attribute__((address_space(1))) unsigned int*)g,
      (__attribute__((address_space(3))) unsigned int*)l, 16, 0, 0);
}

// 3-deep pipeline buffers (T3/T4: counted vmcnt across raw s_barrier; the
// per-tile __syncthreads drain was the measured 2.2us/K-tile wall R3-R12).
typedef f16 AsT[3][4][256][8];  // 48 KB
typedef f16 BsT[3][4][128][8];  // 24 KB

#define WAITVM(vm)                                                        \
  asm volatile("s_waitcnt vmcnt(" #vm ") lgkmcnt(0)" ::: "memory");       \
  __builtin_amdgcn_sched_barrier(0);                                      \
  __builtin_amdgcn_s_barrier();                                           \
  __builtin_amdgcn_sched_barrier(0)

#define ENDBAR                                                            \
  __builtin_amdgcn_sched_barrier(0);                                      \
  __builtin_amdgcn_s_barrier()

// ---------------- layer-1 GEMM body ----------------
// BM=256 rows/block, BN=128 cols; half: 0 -> Wl (P), 1 -> Wr (Q).
// Per-stage vm ops: 2 d-loads (consumed in-stage) + 1 gld_lds(B).
// MODE 1: bond [N][12], K=480 (40 filters). MODE 2: angle [N][144], K=1152.
template <int MODE, int K>
__device__ __forceinline__ void gemm1_body(
    const float* __restrict__ Asrc, const f16* __restrict__ Wcat,
    f16* __restrict__ P, f16* __restrict__ Q, int n, AsT& As, BsT& Bs) {
  const int tid = threadIdx.x;
  const int lane = tid & 63;
  const int wid = tid >> 6;
  const int wr = wid >> 1;  // 0..3 (64-row strip)
  const int wc = wid & 1;   // 0..1 (64-col strip)
  const int row0 = blockIdx.x * 256;
  const int half = blockIdx.y;
  const f16* Wh = Wcat + (size_t)half * 128 * K;
  f16* outp = half ? Q : P;

  const int bcol = tid & 127;
  const int bkb = tid >> 7;  // 0..3
  const int sArow = tid & 255;
  const int sAkb0 = tid >> 8;  // 0..1 (+2 on pass 1)
  int arow = row0 + sArow;
  if (arow >= n) arow = n - 1;

  f32x4 acc[4][4];
#pragma unroll
  for (int m = 0; m < 4; ++m)
#pragma unroll
    for (int q = 0; q < 4; ++q) acc[m][q] = (f32x4)0.f;

  auto stage = [&](int buf, int t) {
    int k0 = t * 32;
    gld_lds16(Wh + (size_t)bcol * K + k0 + bkb * 8, &Bs[buf][bkb][bcol][0]);
#pragma unroll
    for (int p = 0; p < 2; ++p) {
      int kb = sAkb0 + 2 * p;
      int kg0 = k0 + kb * 8;
      f16 v[8];
      if constexpr (MODE == 1) {
        int jn = kg0 / 40;  // 40 % 8 == 0: 8-block never crosses a filter group
        int kk0 = kg0 - jn * 40;
        float d = Asrc[arow * NEIGH + jn];
#pragma unroll
        for (int j = 0; j < 8; ++j) {
          float t2 = d - (kk0 + j) * (8.0f / 39.0f);
          v[j] = (f16)__expf(-t2 * t2 * 25.0f);  // gamma = 8/40
        }
      } else {
        int jn = kg0 >> 3;
        float d = Asrc[arow * 144 + jn];
#pragma unroll
        for (int j = 0; j < 8; ++j) {
          float t2 = d - (-1.0f + j * (2.0f / 7.0f));
          v[j] = (f16)__expf(-t2 * t2 * 16.0f);  // gamma = 2/8
        }
      }
      *(f16x8*)&As[buf][kb][sArow][0] = *(const f16x8*)v;
    }
  };

  constexpr int NT = K / 32;
  stage(0, 0);
  stage(1, 1);
  for (int t = 0; t < NT; ++t) {
    if (t + 2 < NT) stage((t + 2) % 3, t + 2);
    // tile t complete per-wave; tiles t+1,t+2 stay in flight across the barrier
    if (t < NT - 2) {
      WAITVM(2);
    } else if (t == NT - 2) {
      WAITVM(1);
    } else {
      WAITVM(0);
    }
    const int buf = t % 3;
    const int kb = lane >> 4;
    const int r16 = lane & 15;
    f16x8 a[4], b[4];
#pragma unroll
    for (int m = 0; m < 4; ++m)
      a[m] = *(const f16x8*)&As[buf][kb][wr * 64 + m * 16 + r16][0];
#pragma unroll
    for (int q = 0; q < 4; ++q)
      b[q] = *(const f16x8*)&Bs[buf][kb][wc * 64 + q * 16 + r16][0];
#pragma unroll
    for (int m = 0; m < 4; ++m)
#pragma unroll
      for (int q = 0; q < 4; ++q)
        acc[m][q] =
            __builtin_amdgcn_mfma_f32_16x16x32_f16(a[m], b[q], acc[m][q], 0, 0, 0);
    ENDBAR;  // protect buf(t%3) from being overwritten by stage(t+3) next iter
  }

  const int crow = (lane >> 4) * 4;
  const int ccol = lane & 15;
#pragma unroll
  for (int m = 0; m < 4; ++m) {
#pragma unroll
    for (int r = 0; r < 4; ++r) {
      int row = row0 + wr * 64 + m * 16 + crow + r;
      if (row < n) {
#pragma unroll
        for (int q = 0; q < 4; ++q)
          outp[(size_t)row * 128 + wc * 64 + q * 16 + ccol] = (f16)acc[m][q][r];
      }
    }
  }
}

// grid (196, 2, 2): y = W-half, z = mode (0 angle K=1152, 1 bond K=480).
__global__ __launch_bounds__(512) void gemm1all(
    const float* __restrict__ angle, const f16* __restrict__ Wa,
    f16* __restrict__ Pa, f16* __restrict__ Qa,
    const float* __restrict__ bond, const f16* __restrict__ Wb,
    f16* __restrict__ Pb, f16* __restrict__ Qb, int n) {
  __shared__ __align__(16) AsT As;
  __shared__ __align__(16) BsT Bs;
  if (blockIdx.z == 0)
    gemm1_body<2, 1152>(angle, Wa, Pa, Qa, n, As, Bs);
  else
    gemm1_body<1, 480>(bond, Wb, Pb, Qb, n, As, Bs);
}

// ---------------- layers 2-3: x' = relu([agg|x] @ Wcat2^T + b) ----------------
// BM=256, BN=128, 512 threads, IN-PLACE ax update (block-local safe).
// Per-stage vm ops: 3 gld_lds -> counted vmcnt 6/3/0.
__global__ __launch_bounds__(512) void gemmL(
    f16* __restrict__ axb, f16* __restrict__ axa, const f16* __restrict__ Wall,
    const float* __restrict__ bb, const float* __restrict__ ba, int lidx, int n) {
  __shared__ __align__(16) AsT As;
  __shared__ __align__(16) BsT Bs;
  const int path = blockIdx.y;
  f16* ax = path ? axa : axb;
  const f16* W = Wall + (size_t)(path * 2 + lidx) * 32768;
  const float* bias = (path ? ba : bb) + lidx * 128;

  const int tid = threadIdx.x;
  const int lane = tid & 63;
  const int wid = tid >> 6;
  const int wr = wid >> 1;  // 0..3
  const int wc = wid & 1;   // 0..1
  const int row0 = blockIdx.x * 256;

  const int bcol = tid & 127;
  const int bkb = tid >> 7;  // 0..3
  const int sArow = tid & 255;
  const int sAkb0 = tid >> 8;  // 0..1
  int arow = row0 + sArow;
  if (arow >= n) arow = n - 1;

  f32x4 acc[4][4];
#pragma unroll
  for (int m = 0; m < 4; ++m)
#pragma unroll
    for (int q = 0; q < 4; ++q) acc[m][q] = (f32x4)0.f;

  auto stage = [&](int buf, int t) {
    int k0 = t * 32;
    gld_lds16(W + (size_t)bcol * 256 + k0 + bkb * 8, &Bs[buf][bkb][bcol][0]);
#pragma unroll
    for (int p = 0; p < 2; ++p) {
      int kb = sAkb0 + 2 * p;
      gld_lds16(ax + (size_t)arow * 256 + k0 + kb * 8, &As[buf][kb][sArow][0]);
    }
  };

  stage(0, 0);
  stage(1, 1);
  for (int t = 0; t < 8; ++t) {
    if (t + 2 < 8) stage((t + 2) % 3, t + 2);
    if (t < 6) {
      WAITVM(6);
    } else if (t == 6) {
      WAITVM(3);
    } else {
      WAITVM(0);
    }
    const int buf = t % 3;
    const int kb = lane >> 4;
    const int r16 = lane & 15;
    f16x8 a[4], b[4];
#pragma unroll
    for (int m = 0; m < 4; ++m)
      a[m] = *(const f16x8*)&As[buf][kb][wr * 64 + m * 16 + r16][0];
#pragma unroll
    for (int q = 0; q < 4; ++q)
      b[q] = *(const f16x8*)&Bs[buf][kb][wc * 64 + q * 16 + r16][0];
#pragma unroll
    for (int m = 0; m < 4; ++m)
#pragma unroll
      for (int q = 0; q < 4; ++q)
        acc[m][q] =
            __builtin_amdgcn_mfma_f32_16x16x32_f16(a[m], b[q], acc[m][q], 0, 0, 0);
    ENDBAR;
  }

  const int crow = (lane >> 4) * 4;
  const int ccol = lane & 15;
#pragma unroll
  for (int m = 0; m < 4; ++m) {
#pragma unroll
    for (int r = 0; r < 4; ++r) {
      int row = row0 + wr * 64 + m * 16 + crow + r;
      if (row < n) {
#pragma unroll
        for (int q = 0; q < 4; ++q) {
          int col = wc * 64 + q * 16 + ccol;
          float v = acc[m][q][r] + bias[col];
          ax[(size_t)row * 256 + 128 + col] = (f16)fmaxf(v, 0.0f);
        }
      }
    }
  }
}

// ---------------- weight conversion ----------------
__global__ void cvtW(const float* __restrict__ Wl, const float* __restrict__ Wr,
                     f16* __restrict__ outp, int K) {
  int c = blockIdx.y;
  int k = blockIdx.x * 256 + threadIdx.x;
  if (k < K)
    outp[(size_t)c * K + k] =
        (f16)((c < 128) ? Wl[(size_t)c * K + k] : Wr[(size_t)(c - 128) * K + k]);
}

__global__ void cvtW_small(const float* __restrict__ Wl_b, const float* __restrict__ Wr_b,
                           const float* __restrict__ Wl_a, const float* __restrict__ Wr_a,
                           f16* __restrict__ outp) {
  int idx = blockIdx.x * 256 + threadIdx.x;  // 4*128*256
  int l = idx >> 15;
  int c = (idx >> 8) & 127;
  int k = idx & 255;
  const float* Wl = (l < 2) ? Wl_b + (size_t)l * 16384 : Wl_a + (size_t)(l - 2) * 16384;
  const float* Wr = (l < 2) ? Wr_b + (size_t)l * 16384 : Wr_a + (size_t)(l - 2) * 16384;
  float v = (k < 128) ? Wl[(size_t)c * 128 + k] : Wr[(size_t)c * 128 + (k - 128)];
  outp[idx] = (f16)v;
}

// ---------------- CSR build ----------------
__global__ void k_count(const int* __restrict__ nbr, int* __restrict__ deg) {
  int e = blockIdx.x * 256 + threadIdx.x;
  if (e < NEDGE) atomicAdd(&deg[nbr[e]], 1);
}
__global__ void k_scan1(const int* __restrict__ deg, int* __restrict__ rowptr,
                        int* __restrict__ bsum) {
  __shared__ int s[256];
  int t = threadIdx.x, i = blockIdx.x * 256 + t;
  int v = (i < N_ATOMS) ? deg[i] : 0;
  s[t] = v;
  __syncthreads();
  for (int off = 1; off < 256; off <<= 1) {
    int x = (t >= off) ? s[t - off] : 0;
    __syncthreads();
    s[t] += x;
    __syncthreads();
  }
  if (i < N_ATOMS) rowptr[i] = s[t] - v;
  if (t == 255) bsum[blockIdx.x] = s[255];
}
__global__ void k_scan2(int* __restrict__ bsum) {
  __shared__ int s[256];
  int t = threadIdx.x;
  int v = (t < NBLK) ? bsum[t] : 0;
  s[t] = v;
  __syncthreads();
  for (int off = 1; off < 256; off <<= 1) {
    int x = (t >= off) ? s[t - off] : 0;
    __syncthreads();
    s[t] += x;
    __syncthreads();
  }
  if (t < NBLK) bsum[t] = s[t] - v;
}
__global__ void k_scan3(int* __restrict__ rowptr, const int* __restrict__ bsum) {
  int i = blockIdx.x * 256 + threadIdx.x;
  if (i < N_ATOMS) rowptr[i] += bsum[blockIdx.x];
  if (i == 0) rowptr[N_ATOMS] = NEDGE;
}
// eidx stores PRE-SCALED byte offsets (src*256) for base+zext(u32) addressing.
__global__ void k_fill(const int* __restrict__ nbr, const int* __restrict__ rowptr,
                       int* __restrict__ cursor, int* __restrict__ eidx) {
  int e = blockIdx.x * 256 + threadIdx.x;
  if (e < NEDGE) {
    int dst = nbr[e];
    int pos = rowptr[dst] + atomicAdd(&cursor[dst], 1);
    eidx[pos] = (e / NEIGH) << 8;  // src atom * 256 bytes (P row)
  }
}

// ---------------- layer-1 finalize: x = relu(mean_j P[src_j] + b + Q) ----------------
__global__ __launch_bounds__(256) void gather_fin1(
    const f16* __restrict__ Pb, const f16* __restrict__ Qb,
    const f16* __restrict__ Pa, const f16* __restrict__ Qa,
    const int* __restrict__ rowptr, const int* __restrict__ eidx,
    const float* __restrict__ bias_b, const float* __restrict__ bias_a,
    f16* __restrict__ axb, f16* __restrict__ axa) {
  const int path = blockIdx.y;
  const char* Pc = (const char*)(path ? Pa : Pb);
  const f16* Q = path ? Qa : Qb;
  const float* bias = path ? bias_a : bias_b;
  f16* ax = path ? axa : axb;
  const int t = threadIdx.x;
  const int a = blockIdx.x * 16 + (t >> 4);
  const int g = (t & 15) * 8;
  const unsigned gb = (unsigned)(t & 15) * 16;
  const int s0 = rowptr[a], s1 = rowptr[a + 1];
  float acc[8];
#pragma unroll
  for (int u = 0; u < 8; ++u) acc[u] = 0.f;
  int j = s0;
  for (; j + 8 <= s1; j += 8) {
    f16x8 v[8];
#pragma unroll
    for (int u = 0; u < 8; ++u)
      v[u] = *(const f16x8*)(Pc + (size_t)((unsigned)eidx[j + u] + gb));
    f16x8 s = ((v[0] + v[1]) + (v[2] + v[3])) + ((v[4] + v[5]) + (v[6] + v[7]));
#pragma unroll
    for (int c = 0; c < 8; ++c) acc[c] += (float)s[c];
  }
  for (; j + 4 <= s1; j += 4) {
    f16x8 v0 = *(const f16x8*)(Pc + (size_t)((unsigned)eidx[j] + gb));
    f16x8 v1 = *(const f16x8*)(Pc + (size_t)((unsigned)eidx[j + 1] + gb));
    f16x8 v2 = *(const f16x8*)(Pc + (size_t)((unsigned)eidx[j + 2] + gb));
    f16x8 v3 = *(const f16x8*)(Pc + (size_t)((unsigned)eidx[j + 3] + gb));
    f16x8 s = (v0 + v1) + (v2 + v3);
#pragma unroll
    for (int c = 0; c < 8; ++c) acc[c] += (float)s[c];
  }
  for (; j < s1; ++j) {
    f16x8 v = *(const f16x8*)(Pc + (size_t)((unsigned)eidx[j] + gb));
#pragma unroll
    for (int c = 0; c < 8; ++c) acc[c] += (float)v[c];
  }
  f16x8 q = *(const f16x8*)&Q[(size_t)a * 128 + g];
  float inv = 1.0f / fmaxf((float)(s1 - s0), 1.0f);
  f16 outv[8];
#pragma unroll
  for (int u = 0; u < 8; ++u) {
    float v = acc[u] * inv + bias[g + u] + (float)q[u];
    outv[u] = (f16)fmaxf(v, 0.0f);
  }
  *(f16x8*)&ax[(size_t)a * 256 + 128 + g] = *(const f16x8*)outv;
}

// ---------------- layers 2-3 aggregation: agg half <- mean_j x[src_j] ----------------
__global__ __launch_bounds__(256) void gather_mean(
    f16* __restrict__ axb, f16* __restrict__ axa,
    const int* __restrict__ rowptr, const int* __restrict__ eidx) {
  f16* ax = blockIdx.y ? axa : axb;
  const char* axc = (const char*)ax;
  const int t = threadIdx.x;
  const int a = blockIdx.x * 16 + (t >> 4);
  const int g = (t & 15) * 8;
  const unsigned gb = 256u + (unsigned)(t & 15) * 16;
  const int s0 = rowptr[a], s1 = rowptr[a + 1];
  float acc[8];
#pragma unroll
  for (int u = 0; u < 8; ++u) acc[u] = 0.f;
  int j = s0;
  for (; j + 8 <= s1; j += 8) {
    f16x8 v[8];
#pragma unroll
    for (int u = 0; u < 8; ++u)
      v[u] = *(const f16x8*)(axc + (size_t)(((unsigned)eidx[j + u] << 1) + gb));
    f16x8 s = ((v[0] + v[1]) + (v[2] + v[3])) + ((v[4] + v[5]) + (v[6] + v[7]));
#pragma unroll
    for (int c = 0; c < 8; ++c) acc[c] += (float)s[c];
  }
  for (; j + 4 <= s1; j += 4) {
    f16x8 v0 = *(const f16x8*)(axc + (size_t)(((unsigned)eidx[j] << 1) + gb));
    f16x8 v1 = *(const f16x8*)(axc + (size_t)(((unsigned)eidx[j + 1] << 1) + gb));
    f16x8 v2 = *(const f16x8*)(axc + (size_t)(((unsigned)eidx[j + 2] << 1) + gb));
    f16x8 v3 = *(const f16x8*)(axc + (size_t)(((unsigned)eidx[j + 3] << 1) + gb));
    f16x8 s = (v0 + v1) + (v2 + v3);
#pragma unroll
    for (int c = 0; c < 8; ++c) acc[c] += (float)s[c];
  }
  for (; j < s1; ++j) {
    f16x8 v = *(const f16x8*)(axc + (size_t)(((unsigned)eidx[j] << 1) + gb));
#pragma unroll
    for (int c = 0; c < 8; ++c) acc[c] += (float)v[c];
  }
  float inv = 1.0f / fmaxf((float)(s1 - s0), 1.0f);
  f16 outv[8];
#pragma unroll
  for (int u = 0; u < 8; ++u) outv[u] = (f16)(acc[u] * inv);
  *(f16x8*)&ax[(size_t)a * 256 + g] = *(const f16x8*)outv;
}

// ---------------- head: pool -> mlp -> mlp -> fc ----------------
__global__ __launch_bounds__(256) void head_kernel(
    const f16* __restrict__ axb, const f16* __restrict__ axa,
    const int* __restrict__ crys, const float* __restrict__ W_mlp,
    const float* __restrict__ b_mlp, const float* __restrict__ W_fc,
    const float* __restrict__ b_fc, float* __restrict__ outp) {
  __shared__ float sh0[256], sh1[256];
  const int cry = blockIdx.x, c = threadIdx.x;
  const int s = crys[2 * cry], e = crys[2 * cry + 1];
  const f16* src = (c < 128) ? axb : axa;
  const int ch = c & 127;
  float sum = 0.f;
  for (int r = s; r < e; ++r) sum += (float)src[(size_t)r * 256 + 128 + ch];
  sh0[c] = sum / fmaxf((float)(e - s), 1.0f);
  __syncthreads();
  {
    const float* wrow = W_mlp + (size_t)c * 256;
    float s2 = b_mlp[c];
#pragma unroll 8
    for (int k = 0; k < 256; k += 4) {
      float4 w = *(const float4*)&wrow[k];
      s2 += sh0[k] * w.x + sh0[k + 1] * w.y + sh0[k + 2] * w.z + sh0[k + 3] * w.w;
    }
    sh1[c] = s2;
  }
  __syncthreads();
  {
    const float* wrow = W_mlp + 65536 + (size_t)c * 256;
    float s2 = b_mlp[256 + c];
#pragma unroll 8
    for (int k = 0; k < 256; k += 4) {
      float4 w = *(const float4*)&wrow[k];
      s2 += sh1[k] * w.x + sh1[k + 1] * w.y + sh1[k + 2] * w.z + sh1[k + 3] * w.w;
    }
    sh0[c] = s2;
  }
  __syncthreads();
  if (c < 2) {
    const float* wrow = W_fc + c * 256;
    float s2 = b_fc[c];
    for (int k = 0; k < 256; ++k) s2 += sh0[k] * wrow[k];
    outp[cry * 2 + c] = s2;
  }
}

extern "C" void kernel_launch(void* const* d_in, const int* in_sizes, int n_in,
                              void* d_out, int out_size, void* d_ws, size_t ws_size,
                              hipStream_t stream) {
  const float* bond  = (const float*)d_in[0];
  const float* angle = (const float*)d_in[1];
  const int*   nbr   = (const int*)d_in[3];
  const int*   crys  = (const int*)d_in[4];
  const float* Wl_b1 = (const float*)d_in[5];
  const float* Wr_b1 = (const float*)d_in[6];
  const float* b_b1  = (const float*)d_in[7];
  const float* Wl_a1 = (const float*)d_in[8];
  const float* Wr_a1 = (const float*)d_in[9];
  const float* b_a1  = (const float*)d_in[10];
  const float* Wl_b  = (const float*)d_in[11];
  const float* Wr_b  = (const float*)d_in[12];
  const float* b_b   = (const float*)d_in[13];
  const float* Wl_a  = (const float*)d_in[14];
  const float* Wr_a  = (const float*)d_in[15];
  const float* b_a   = (const float*)d_in[16];
  const float* W_mlp = (const float*)d_in[17];
  const float* b_mlp = (const float*)d_in[18];
  const float* W_fc  = (const float*)d_in[19];
  const float* b_fc  = (const float*)d_in[20];

  char* w = (char*)d_ws;
  auto alloc = [&](size_t bytes) {
    void* p = (void*)w;
    w += (bytes + 255) & ~(size_t)255;
    return p;
  };
  f16* axb = (f16*)alloc((size_t)N_ATOMS * 256 * 2);
  f16* axa = (f16*)alloc((size_t)N_ATOMS * 256 * 2);
  f16* Pb  = (f16*)alloc((size_t)N_ATOMS * 128 * 2);
  f16* Qb  = (f16*)alloc((size_t)N_ATOMS * 128 * 2);
  f16* Pa  = (f16*)alloc((size_t)N_ATOMS * 128 * 2);
  f16* Qa  = (f16*)alloc((size_t)N_ATOMS * 128 * 2);
  f16* Wb1c = (f16*)alloc((size_t)256 * 480 * 2);
  f16* Wa1c = (f16*)alloc((size_t)256 * 1152 * 2);
  f16* Wsm  = (f16*)alloc((size_t)4 * 128 * 256 * 2);
  // deg+cursor as ONE contiguous block: the single memset must cover BOTH
  // (0xAA re-poison between timed replays otherwise leaves cursor garbage).
  int* deg    = (int*)alloc((size_t)2 * N_ATOMS * 4);
  int* cursor = deg + N_ATOMS;
  int* rowptr = (int*)alloc((size_t)(N_ATOMS + 1) * 4);
  int* eidx   = (int*)alloc((size_t)NEDGE * 4);
  int* bsum   = (int*)alloc(256 * 4);

  // weights -> fp16
  cvtW<<<dim3(2, 256), 256, 0, stream>>>(Wl_b1, Wr_b1, Wb1c, 480);
  cvtW<<<dim3(5, 256), 256, 0, stream>>>(Wl_a1, Wr_a1, Wa1c, 1152);
  cvtW_small<<<512, 256, 0, stream>>>(Wl_b, Wr_b, Wl_a, Wr_a, Wsm);

  // CSR build
  hipMemsetAsync(deg, 0, (size_t)2 * N_ATOMS * 4, stream);
  k_count<<<(NEDGE + 255) / 256, 256, 0, stream>>>(nbr, deg);
  k_scan1<<<NBLK, 256, 0, stream>>>(deg, rowptr, bsum);
  k_scan2<<<1, 256, 0, stream>>>(bsum);
  k_scan3<<<NBLK, 256, 0, stream>>>(rowptr, bsum);
  k_fill<<<(NEDGE + 255) / 256, 256, 0, stream>>>(nbr, rowptr, cursor, eidx);

  const int GT = (N_ATOMS + 255) / 256;  // 196
  const int AG = N_ATOMS / 16;           // 3125

  // layer 1: single dispatch covers angle+bond x both W-halves
  gemm1all<<<dim3(GT, 2, 2), 512, 0, stream>>>(angle, Wa1c, Pa, Qa,
                                               bond, Wb1c, Pb, Qb, N_ATOMS);
  gather_fin1<<<dim3(AG, 2), 256, 0, stream>>>(Pb, Qb, Pa, Qa, rowptr, eidx,
                                               b_b1, b_a1, axb, axa);

  // layers 2-3 (aggregate-then-project, in-place ax)
  for (int l = 0; l < 2; ++l) {
    gather_mean<<<dim3(AG, 2), 256, 0, stream>>>(axb, axa, rowptr, eidx);
    gemmL<<<dim3(GT, 2), 512, 0, stream>>>(axb, axa, Wsm, b_b, b_a, l, N_ATOMS);
  }

  // head
  head_kernel<<<NCRYS, 256, 0, stream>>>(axb, axa, crys, W_mlp, b_mlp, W_fc, b_fc,
                                         (float*)d_out);
}

// Round 14
// 399.631 us; speedup vs baseline: 1.1605x; 1.0107x over previous
//
#include <hip/hip_runtime.h>

typedef _Float16 f16;
typedef _Float16 f16x8 __attribute__((ext_vector_type(8)));
typedef float f32x4 __attribute__((ext_vector_type(4)));

#define N_ATOMS 50000
#define NEIGH   12
#define NEDGE   (N_ATOMS * NEIGH)
#define NCRYS   500
#define NBLK    196  // ceil(50000/256)

__device__ __forceinline__ void gld_lds16(const void* g, void* l) {
  __builtin_amdgcn_global_load_lds(
      (const __attribute__((address_space(1))) unsigned int*)g,
      (__attribute__((address_space(3))) unsigned int*)l, 16, 0, 0);
}

// 3-deep pipeline buffers (T3/T4 counted vmcnt across raw s_barrier).
typedef f16 AsT[3][4][256][8];  // 48 KB
typedef f16 BsT[3][4][128][8];  // 24 KB

#define WAITVM(vm)                                                        \
  asm volatile("s_waitcnt vmcnt(" #vm ") lgkmcnt(0)" ::: "memory");       \
  __builtin_amdgcn_sched_barrier(0);                                      \
  __builtin_amdgcn_s_barrier();                                           \
  __builtin_amdgcn_sched_barrier(0)

#define ENDBAR                                                            \
  __builtin_amdgcn_sched_barrier(0);                                      \
  __builtin_amdgcn_s_barrier()

// ---------------- layer-1 GEMM body ----------------
// BM=256 rows/block, BN=128 cols; half: 0 -> Wl (P), 1 -> Wr (Q).
// R13 bug fixed: d-loads are now issued one iteration AHEAD of their exp
// consumption (dA/dB register rotation), so the compiler's implicit wait is
// a counted vmcnt(3) instead of an effective full drain (in-order vmcnt
// retirement made "wait for just-issued d" == "wait for everything").
// MODE 1: bond [N][12], K=480 (40 filters). MODE 2: angle [N][144], K=1152.
template <int MODE, int K>
__device__ __forceinline__ void gemm1_body(
    const float* __restrict__ Asrc, const f16* __restrict__ Wcat,
    f16* __restrict__ P, f16* __restrict__ Q, int n, AsT& As, BsT& Bs) {
  constexpr int CIN = (MODE == 1) ? 12 : 144;
  constexpr int NT = K / 32;
  const int tid = threadIdx.x;
  const int lane = tid & 63;
  const int wid = tid >> 6;
  const int wr = wid >> 1;  // 0..3 (64-row strip)
  const int wc = wid & 1;   // 0..1 (64-col strip)
  const int row0 = blockIdx.x * 256;
  const int half = blockIdx.y;
  const f16* Wh = Wcat + (size_t)half * 128 * K;
  f16* outp = half ? Q : P;

  const int bcol = tid & 127;
  const int bkb = tid >> 7;  // 0..3
  const int sArow = tid & 255;
  const int sAkb0 = tid >> 8;  // 0..1 (+2 on pass 1)
  int arow = row0 + sArow;
  if (arow >= n) arow = n - 1;

  f32x4 acc[4][4];
#pragma unroll
  for (int m = 0; m < 4; ++m)
#pragma unroll
    for (int q = 0; q < 4; ++q) acc[m][q] = (f32x4)0.f;

  auto daddr = [&](int t, int p) -> const float* {
    int kb = sAkb0 + 2 * p;
    int kg0 = t * 32 + kb * 8;
    int jn = (MODE == 1) ? kg0 / 40 : (kg0 >> 3);
    return &Asrc[(size_t)arow * CIN + jn];
  };
  auto bload = [&](int t) {
    gld_lds16(Wh + (size_t)bcol * K + t * 32 + bkb * 8, &Bs[t % 3][bkb][bcol][0]);
  };
  auto expwrite = [&](int t, const float* d2) {
#pragma unroll
    for (int p = 0; p < 2; ++p) {
      int kb = sAkb0 + 2 * p;
      int kg0 = t * 32 + kb * 8;
      float d = d2[p];
      f16 v[8];
      if constexpr (MODE == 1) {
        int jn = kg0 / 40;  // 40 % 8 == 0: 8-block never crosses a filter group
        int kk0 = kg0 - jn * 40;
#pragma unroll
        for (int j = 0; j < 8; ++j) {
          float t2 = d - (kk0 + j) * (8.0f / 39.0f);
          v[j] = (f16)__expf(-t2 * t2 * 25.0f);  // gamma = 8/40
        }
      } else {
#pragma unroll
        for (int j = 0; j < 8; ++j) {
          float t2 = d - (-1.0f + j * (2.0f / 7.0f));
          v[j] = (f16)__expf(-t2 * t2 * 16.0f);  // gamma = 2/8
        }
      }
      *(f16x8*)&As[t % 3][kb][sArow][0] = *(const f16x8*)v;
    }
  };

  float dA[2], dB[2];
  // prologue: B for tiles 0,1 in flight; d(2) prefetched; tiles 0,1 exp inline
  bload(0);
  bload(1);
  dA[0] = *daddr(2, 0);
  dA[1] = *daddr(2, 1);
  {
    float d0[2] = {*daddr(0, 0), *daddr(0, 1)};
    expwrite(0, d0);
    float d1[2] = {*daddr(1, 0), *daddr(1, 1)};
    expwrite(1, d1);
  }

  for (int t = 0; t < NT; ++t) {
    if (t + 2 < NT) bload(t + 2);
    if (t + 3 < NT) {
      dB[0] = *daddr(t + 3, 0);
      dB[1] = *daddr(t + 3, 1);
    }
    if (t + 2 < NT) expwrite(t + 2, dA);  // implicit counted wait on dA only
    if (t < NT - 3) {
      WAITVM(3);  // newest 3 = B(t+2), d(t+3)x2 stay in flight; B(t) is landed
    } else {
      WAITVM(0);  // tail: precise drain
    }
    const int buf = t % 3;
    const int kb = lane >> 4;
    const int r16 = lane & 15;
    f16x8 a[4], b[4];
#pragma unroll
    for (int m = 0; m < 4; ++m)
      a[m] = *(const f16x8*)&As[buf][kb][wr * 64 + m * 16 + r16][0];
#pragma unroll
    for (int q = 0; q < 4; ++q)
      b[q] = *(const f16x8*)&Bs[buf][kb][wc * 64 + q * 16 + r16][0];
#pragma unroll
    for (int m = 0; m < 4; ++m)
#pragma unroll
      for (int q = 0; q < 4; ++q)
        acc[m][q] =
            __builtin_amdgcn_mfma_f32_16x16x32_f16(a[m], b[q], acc[m][q], 0, 0, 0);
    ENDBAR;  // protect buf(t%3) from stage(t+3) next iter
    dA[0] = dB[0];
    dA[1] = dB[1];
  }

  const int crow = (lane >> 4) * 4;
  const int ccol = lane & 15;
#pragma unroll
  for (int m = 0; m < 4; ++m) {
#pragma unroll
    for (int r = 0; r < 4; ++r) {
      int row = row0 + wr * 64 + m * 16 + crow + r;
      if (row < n) {
#pragma unroll
        for (int q = 0; q < 4; ++q)
          outp[(size_t)row * 128 + wc * 64 + q * 16 + ccol] = (f16)acc[m][q][r];
      }
    }
  }
}

// grid (196, 2, 2): y = W-half, z = mode (0 angle K=1152, 1 bond K=480).
__global__ __launch_bounds__(512) void gemm1all(
    const float* __restrict__ angle, const f16* __restrict__ Wa,
    f16* __restrict__ Pa, f16* __restrict__ Qa,
    const float* __restrict__ bond, const f16* __restrict__ Wb,
    f16* __restrict__ Pb, f16* __restrict__ Qb, int n) {
  __shared__ __align__(16) AsT As;
  __shared__ __align__(16) BsT Bs;
  if (blockIdx.z == 0)
    gemm1_body<2, 1152>(angle, Wa, Pa, Qa, n, As, Bs);
  else
    gemm1_body<1, 480>(bond, Wb, Pb, Qb, n, As, Bs);
}

// ---------------- layers 2-3: x' = relu([agg|x] @ Wcat2^T + b) ----------------
// BM=256, BN=128, 512 threads, IN-PLACE ax update (block-local safe).
// Per-stage vm ops: 3 gld_lds -> counted vmcnt 6/3/0 (all-gld_lds: no in-stage
// consumption, so the R13 counted scheme is already correct here).
__global__ __launch_bounds__(512) void gemmL(
    f16* __restrict__ axb, f16* __restrict__ axa, const f16* __restrict__ Wall,
    const float* __restrict__ bb, const float* __restrict__ ba, int lidx, int n) {
  __shared__ __align__(16) AsT As;
  __shared__ __align__(16) BsT Bs;
  const int path = blockIdx.y;
  f16* ax = path ? axa : axb;
  const f16* W = Wall + (size_t)(path * 2 + lidx) * 32768;
  const float* bias = (path ? ba : bb) + lidx * 128;

  const int tid = threadIdx.x;
  const int lane = tid & 63;
  const int wid = tid >> 6;
  const int wr = wid >> 1;  // 0..3
  const int wc = wid & 1;   // 0..1
  const int row0 = blockIdx.x * 256;

  const int bcol = tid & 127;
  const int bkb = tid >> 7;  // 0..3
  const int sArow = tid & 255;
  const int sAkb0 = tid >> 8;  // 0..1
  int arow = row0 + sArow;
  if (arow >= n) arow = n - 1;

  f32x4 acc[4][4];
#pragma unroll
  for (int m = 0; m < 4; ++m)
#pragma unroll
    for (int q = 0; q < 4; ++q) acc[m][q] = (f32x4)0.f;

  auto stage = [&](int buf, int t) {
    int k0 = t * 32;
    gld_lds16(W + (size_t)bcol * 256 + k0 + bkb * 8, &Bs[buf][bkb][bcol][0]);
#pragma unroll
    for (int p = 0; p < 2; ++p) {
      int kb = sAkb0 + 2 * p;
      gld_lds16(ax + (size_t)arow * 256 + k0 + kb * 8, &As[buf][kb][sArow][0]);
    }
  };

  stage(0, 0);
  stage(1, 1);
  for (int t = 0; t < 8; ++t) {
    if (t + 2 < 8) stage((t + 2) % 3, t + 2);
    if (t < 6) {
      WAITVM(6);
    } else if (t == 6) {
      WAITVM(3);
    } else {
      WAITVM(0);
    }
    const int buf = t % 3;
    const int kb = lane >> 4;
    const int r16 = lane & 15;
    f16x8 a[4], b[4];
#pragma unroll
    for (int m = 0; m < 4; ++m)
      a[m] = *(const f16x8*)&As[buf][kb][wr * 64 + m * 16 + r16][0];
#pragma unroll
    for (int q = 0; q < 4; ++q)
      b[q] = *(const f16x8*)&Bs[buf][kb][wc * 64 + q * 16 + r16][0];
#pragma unroll
    for (int m = 0; m < 4; ++m)
#pragma unroll
      for (int q = 0; q < 4; ++q)
        acc[m][q] =
            __builtin_amdgcn_mfma_f32_16x16x32_f16(a[m], b[q], acc[m][q], 0, 0, 0);
    ENDBAR;
  }

  const int crow = (lane >> 4) * 4;
  const int ccol = lane & 15;
#pragma unroll
  for (int m = 0; m < 4; ++m) {
#pragma unroll
    for (int r = 0; r < 4; ++r) {
      int row = row0 + wr * 64 + m * 16 + crow + r;
      if (row < n) {
#pragma unroll
        for (int q = 0; q < 4; ++q) {
          int col = wc * 64 + q * 16 + ccol;
          float v = acc[m][q][r] + bias[col];
          ax[(size_t)row * 256 + 128 + col] = (f16)fmaxf(v, 0.0f);
        }
      }
    }
  }
}

// ---------------- weight conversion ----------------
__global__ void cvtW(const float* __restrict__ Wl, const float* __restrict__ Wr,
                     f16* __restrict__ outp, int K) {
  int c = blockIdx.y;
  int k = blockIdx.x * 256 + threadIdx.x;
  if (k < K)
    outp[(size_t)c * K + k] =
        (f16)((c < 128) ? Wl[(size_t)c * K + k] : Wr[(size_t)(c - 128) * K + k]);
}

__global__ void cvtW_small(const float* __restrict__ Wl_b, const float* __restrict__ Wr_b,
                           const float* __restrict__ Wl_a, const float* __restrict__ Wr_a,
                           f16* __restrict__ outp) {
  int idx = blockIdx.x * 256 + threadIdx.x;  // 4*128*256
  int l = idx >> 15;
  int c = (idx >> 8) & 127;
  int k = idx & 255;
  const float* Wl = (l < 2) ? Wl_b + (size_t)l * 16384 : Wl_a + (size_t)(l - 2) * 16384;
  const float* Wr = (l < 2) ? Wr_b + (size_t)l * 16384 : Wr_a + (size_t)(l - 2) * 16384;
  float v = (k < 128) ? Wl[(size_t)c * 128 + k] : Wr[(size_t)c * 128 + (k - 128)];
  outp[idx] = (f16)v;
}

// ---------------- CSR build ----------------
__global__ void k_count(const int* __restrict__ nbr, int* __restrict__ deg) {
  int e = blockIdx.x * 256 + threadIdx.x;
  if (e < NEDGE) atomicAdd(&deg[nbr[e]], 1);
}
__global__ void k_scan1(const int* __restrict__ deg, int* __restrict__ rowptr,
                        int* __restrict__ bsum) {
  __shared__ int s[256];
  int t = threadIdx.x, i = blockIdx.x * 256 + t;
  int v = (i < N_ATOMS) ? deg[i] : 0;
  s[t] = v;
  __syncthreads();
  for (int off = 1; off < 256; off <<= 1) {
    int x = (t >= off) ? s[t - off] : 0;
    __syncthreads();
    s[t] += x;
    __syncthreads();
  }
  if (i < N_ATOMS) rowptr[i] = s[t] - v;
  if (t == 255) bsum[blockIdx.x] = s[255];
}
__global__ void k_scan2(int* __restrict__ bsum) {
  __shared__ int s[256];
  int t = threadIdx.x;
  int v = (t < NBLK) ? bsum[t] : 0;
  s[t] = v;
  __syncthreads();
  for (int off = 1; off < 256; off <<= 1) {
    int x = (t >= off) ? s[t - off] : 0;
    __syncthreads();
    s[t] += x;
    __syncthreads();
  }
  if (t < NBLK) bsum[t] = s[t] - v;
}
__global__ void k_scan3(int* __restrict__ rowptr, const int* __restrict__ bsum) {
  int i = blockIdx.x * 256 + threadIdx.x;
  if (i < N_ATOMS) rowptr[i] += bsum[blockIdx.x];
  if (i == 0) rowptr[N_ATOMS] = NEDGE;
}
// eidx stores PRE-SCALED byte offsets (src*256) for base+zext(u32) addressing.
__global__ void k_fill(const int* __restrict__ nbr, const int* __restrict__ rowptr,
                       int* __restrict__ cursor, int* __restrict__ eidx) {
  int e = blockIdx.x * 256 + threadIdx.x;
  if (e < NEDGE) {
    int dst = nbr[e];
    int pos = rowptr[dst] + atomicAdd(&cursor[dst], 1);
    eidx[pos] = (e / NEIGH) << 8;  // src atom * 256 bytes (P row)
  }
}

// ---------------- layer-1 finalize: x = relu(mean_j P[src_j] + b + Q) ----------------
__global__ __launch_bounds__(256) void gather_fin1(
    const f16* __restrict__ Pb, const f16* __restrict__ Qb,
    const f16* __restrict__ Pa, const f16* __restrict__ Qa,
    const int* __restrict__ rowptr, const int* __restrict__ eidx,
    const float* __restrict__ bias_b, const float* __restrict__ bias_a,
    f16* __restrict__ axb, f16* __restrict__ axa) {
  const int path = blockIdx.y;
  const char* Pc = (const char*)(path ? Pa : Pb);
  const f16* Q = path ? Qa : Qb;
  const float* bias = path ? bias_a : bias_b;
  f16* ax = path ? axa : axb;
  const int t = threadIdx.x;
  const int a = blockIdx.x * 16 + (t >> 4);
  const int g = (t & 15) * 8;
  const unsigned gb = (unsigned)(t & 15) * 16;
  const int s0 = rowptr[a], s1 = rowptr[a + 1];
  float acc[8];
#pragma unroll
  for (int u = 0; u < 8; ++u) acc[u] = 0.f;
  int j = s0;
  for (; j + 8 <= s1; j += 8) {
    f16x8 v[8];
#pragma unroll
    for (int u = 0; u < 8; ++u)
      v[u] = *(const f16x8*)(Pc + (size_t)((unsigned)eidx[j + u] + gb));
    f16x8 s = ((v[0] + v[1]) + (v[2] + v[3])) + ((v[4] + v[5]) + (v[6] + v[7]));
#pragma unroll
    for (int c = 0; c < 8; ++c) acc[c] += (float)s[c];
  }
  for (; j + 4 <= s1; j += 4) {
    f16x8 v0 = *(const f16x8*)(Pc + (size_t)((unsigned)eidx[j] + gb));
    f16x8 v1 = *(const f16x8*)(Pc + (size_t)((unsigned)eidx[j + 1] + gb));
    f16x8 v2 = *(const f16x8*)(Pc + (size_t)((unsigned)eidx[j + 2] + gb));
    f16x8 v3 = *(const f16x8*)(Pc + (size_t)((unsigned)eidx[j + 3] + gb));
    f16x8 s = (v0 + v1) + (v2 + v3);
#pragma unroll
    for (int c = 0; c < 8; ++c) acc[c] += (float)s[c];
  }
  for (; j < s1; ++j) {
    f16x8 v = *(const f16x8*)(Pc + (size_t)((unsigned)eidx[j] + gb));
#pragma unroll
    for (int c = 0; c < 8; ++c) acc[c] += (float)v[c];
  }
  f16x8 q = *(const f16x8*)&Q[(size_t)a * 128 + g];
  float inv = 1.0f / fmaxf((float)(s1 - s0), 1.0f);
  f16 outv[8];
#pragma unroll
  for (int u = 0; u < 8; ++u) {
    float v = acc[u] * inv + bias[g + u] + (float)q[u];
    outv[u] = (f16)fmaxf(v, 0.0f);
  }
  *(f16x8*)&ax[(size_t)a * 256 + 128 + g] = *(const f16x8*)outv;
}

// ---------------- layers 2-3 aggregation: agg half <- mean_j x[src_j] ----------------
__global__ __launch_bounds__(256) void gather_mean(
    f16* __restrict__ axb, f16* __restrict__ axa,
    const int* __restrict__ rowptr, const int* __restrict__ eidx) {
  f16* ax = blockIdx.y ? axa : axb;
  const char* axc = (const char*)ax;
  const int t = threadIdx.x;
  const int a = blockIdx.x * 16 + (t >> 4);
  const int g = (t & 15) * 8;
  const unsigned gb = 256u + (unsigned)(t & 15) * 16;
  const int s0 = rowptr[a], s1 = rowptr[a + 1];
  float acc[8];
#pragma unroll
  for (int u = 0; u < 8; ++u) acc[u] = 0.f;
  int j = s0;
  for (; j + 8 <= s1; j += 8) {
    f16x8 v[8];
#pragma unroll
    for (int u = 0; u < 8; ++u)
      v[u] = *(const f16x8*)(axc + (size_t)(((unsigned)eidx[j + u] << 1) + gb));
    f16x8 s = ((v[0] + v[1]) + (v[2] + v[3])) + ((v[4] + v[5]) + (v[6] + v[7]));
#pragma unroll
    for (int c = 0; c < 8; ++c) acc[c] += (float)s[c];
  }
  for (; j + 4 <= s1; j += 4) {
    f16x8 v0 = *(const f16x8*)(axc + (size_t)(((unsigned)eidx[j] << 1) + gb));
    f16x8 v1 = *(const f16x8*)(axc + (size_t)(((unsigned)eidx[j + 1] << 1) + gb));
    f16x8 v2 = *(const f16x8*)(axc + (size_t)(((unsigned)eidx[j + 2] << 1) + gb));
    f16x8 v3 = *(const f16x8*)(axc + (size_t)(((unsigned)eidx[j + 3] << 1) + gb));
    f16x8 s = (v0 + v1) + (v2 + v3);
#pragma unroll
    for (int c = 0; c < 8; ++c) acc[c] += (float)s[c];
  }
  for (; j < s1; ++j) {
    f16x8 v = *(const f16x8*)(axc + (size_t)(((unsigned)eidx[j] << 1) + gb));
#pragma unroll
    for (int c = 0; c < 8; ++c) acc[c] += (float)v[c];
  }
  float inv = 1.0f / fmaxf((float)(s1 - s0), 1.0f);
  f16 outv[8];
#pragma unroll
  for (int u = 0; u < 8; ++u) outv[u] = (f16)(acc[u] * inv);
  *(f16x8*)&ax[(size_t)a * 256 + g] = *(const f16x8*)outv;
}

// ---------------- head: pool -> mlp -> mlp -> fc ----------------
__global__ __launch_bounds__(256) void head_kernel(
    const f16* __restrict__ axb, const f16* __restrict__ axa,
    const int* __restrict__ crys, const float* __restrict__ W_mlp,
    const float* __restrict__ b_mlp, const float* __restrict__ W_fc,
    const float* __restrict__ b_fc, float* __restrict__ outp) {
  __shared__ float sh0[256], sh1[256];
  const int cry = blockIdx.x, c = threadIdx.x;
  const int s = crys[2 * cry], e = crys[2 * cry + 1];
  const f16* src = (c < 128) ? axb : axa;
  const int ch = c & 127;
  float sum = 0.f;
  for (int r = s; r < e; ++r) sum += (float)src[(size_t)r * 256 + 128 + ch];
  sh0[c] = sum / fmaxf((float)(e - s), 1.0f);
  __syncthreads();
  {
    const float* wrow = W_mlp + (size_t)c * 256;
    float s2 = b_mlp[c];
#pragma unroll 8
    for (int k = 0; k < 256; k += 4) {
      float4 w = *(const float4*)&wrow[k];
      s2 += sh0[k] * w.x + sh0[k + 1] * w.y + sh0[k + 2] * w.z + sh0[k + 3] * w.w;
    }
    sh1[c] = s2;
  }
  __syncthreads();
  {
    const float* wrow = W_mlp + 65536 + (size_t)c * 256;
    float s2 = b_mlp[256 + c];
#pragma unroll 8
    for (int k = 0; k < 256; k += 4) {
      float4 w = *(const float4*)&wrow[k];
      s2 += sh1[k] * w.x + sh1[k + 1] * w.y + sh1[k + 2] * w.z + sh1[k + 3] * w.w;
    }
    sh0[c] = s2;
  }
  __syncthreads();
  if (c < 2) {
    const float* wrow = W_fc + c * 256;
    float s2 = b_fc[c];
    for (int k = 0; k < 256; ++k) s2 += sh0[k] * wrow[k];
    outp[cry * 2 + c] = s2;
  }
}

extern "C" void kernel_launch(void* const* d_in, const int* in_sizes, int n_in,
                              void* d_out, int out_size, void* d_ws, size_t ws_size,
                              hipStream_t stream) {
  const float* bond  = (const float*)d_in[0];
  const float* angle = (const float*)d_in[1];
  const int*   nbr   = (const int*)d_in[3];
  const int*   crys  = (const int*)d_in[4];
  const float* Wl_b1 = (const float*)d_in[5];
  const float* Wr_b1 = (const float*)d_in[6];
  const float* b_b1  = (const float*)d_in[7];
  const float* Wl_a1 = (const float*)d_in[8];
  const float* Wr_a1 = (const float*)d_in[9];
  const float* b_a1  = (const float*)d_in[10];
  const float* Wl_b  = (const float*)d_in[11];
  const float* Wr_b  = (const float*)d_in[12];
  const float* b_b   = (const float*)d_in[13];
  const float* Wl_a  = (const float*)d_in[14];
  const float* Wr_a  = (const float*)d_in[15];
  const float* b_a   = (const float*)d_in[16];
  const float* W_mlp = (const float*)d_in[17];
  const float* b_mlp = (const float*)d_in[18];
  const float* W_fc  = (const float*)d_in[19];
  const float* b_fc  = (const float*)d_in[20];

  char* w = (char*)d_ws;
  auto alloc = [&](size_t bytes) {
    void* p = (void*)w;
    w += (bytes + 255) & ~(size_t)255;
    return p;
  };
  f16* axb = (f16*)alloc((size_t)N_ATOMS * 256 * 2);
  f16* axa = (f16*)alloc((size_t)N_ATOMS * 256 * 2);
  f16* Pb  = (f16*)alloc((size_t)N_ATOMS * 128 * 2);
  f16* Qb  = (f16*)alloc((size_t)N_ATOMS * 128 * 2);
  f16* Pa  = (f16*)alloc((size_t)N_ATOMS * 128 * 2);
  f16* Qa  = (f16*)alloc((size_t)N_ATOMS * 128 * 2);
  f16* Wb1c = (f16*)alloc((size_t)256 * 480 * 2);
  f16* Wa1c = (f16*)alloc((size_t)256 * 1152 * 2);
  f16* Wsm  = (f16*)alloc((size_t)4 * 128 * 256 * 2);
  // deg+cursor as ONE contiguous block: the single memset must cover BOTH
  // (0xAA re-poison between timed replays otherwise leaves cursor garbage).
  int* deg    = (int*)alloc((size_t)2 * N_ATOMS * 4);
  int* cursor = deg + N_ATOMS;
  int* rowptr = (int*)alloc((size_t)(N_ATOMS + 1) * 4);
  int* eidx   = (int*)alloc((size_t)NEDGE * 4);
  int* bsum   = (int*)alloc(256 * 4);

  // weights -> fp16
  cvtW<<<dim3(2, 256), 256, 0, stream>>>(Wl_b1, Wr_b1, Wb1c, 480);
  cvtW<<<dim3(5, 256), 256, 0, stream>>>(Wl_a1, Wr_a1, Wa1c, 1152);
  cvtW_small<<<512, 256, 0, stream>>>(Wl_b, Wr_b, Wl_a, Wr_a, Wsm);

  // CSR build
  hipMemsetAsync(deg, 0, (size_t)2 * N_ATOMS * 4, stream);
  k_count<<<(NEDGE + 255) / 256, 256, 0, stream>>>(nbr, deg);
  k_scan1<<<NBLK, 256, 0, stream>>>(deg, rowptr, bsum);
  k_scan2<<<1, 256, 0, stream>>>(bsum);
  k_scan3<<<NBLK, 256, 0, stream>>>(rowptr, bsum);
  k_fill<<<(NEDGE + 255) / 256, 256, 0, stream>>>(nbr, rowptr, cursor, eidx);

  const int GT = (N_ATOMS + 255) / 256;  // 196
  const int AG = N_ATOMS / 16;           // 3125

  // layer 1: single dispatch covers angle+bond x both W-halves
  gemm1all<<<dim3(GT, 2, 2), 512, 0, stream>>>(angle, Wa1c, Pa, Qa,
                                               bond, Wb1c, Pb, Qb, N_ATOMS);
  gather_fin1<<<dim3(AG, 2), 256, 0, stream>>>(Pb, Qb, Pa, Qa, rowptr, eidx,
                                               b_b1, b_a1, axb, axa);

  // layers 2-3 (aggregate-then-project, in-place ax)
  for (int l = 0; l < 2; ++l) {
    gather_mean<<<dim3(AG, 2), 256, 0, stream>>>(axb, axa, rowptr, eidx);
    gemmL<<<dim3(GT, 2), 512, 0, stream>>>(axb, axa, Wsm, b_b, b_a, l, N_ATOMS);
  }

  // head
  head_kernel<<<NCRYS, 256, 0, stream>>>(axb, axa, crys, W_mlp, b_mlp, W_fc, b_fc,
                                         (float*)d_out);
}

// Round 15
// 392.833 us; speedup vs baseline: 1.1805x; 1.0173x over previous
//
#include <hip/hip_runtime.h>

typedef _Float16 f16;
typedef _Float16 f16x8 __attribute__((ext_vector_type(8)));
typedef float f32x4 __attribute__((ext_vector_type(4)));

#define N_ATOMS 50000
#define NEIGH   12
#define NEDGE   (N_ATOMS * NEIGH)
#define NCRYS   500
#define NBLK    196  // ceil(50000/256)

__device__ __forceinline__ void gld_lds16(const void* g, void* l) {
  __builtin_amdgcn_global_load_lds(
      (const __attribute__((address_space(1))) unsigned int*)g,
      (__attribute__((address_space(3))) unsigned int*)l, 16, 0, 0);
}

// 3-deep pipeline buffers (T3/T4 counted vmcnt across raw s_barrier).
typedef f16 AsT[3][4][256][8];  // 48 KB
typedef f16 BsT[3][4][128][8];  // 24 KB

#define WAITVM(vm)                                                        \
  asm volatile("s_waitcnt vmcnt(" #vm ") lgkmcnt(0)" ::: "memory");       \
  __builtin_amdgcn_sched_barrier(0);                                      \
  __builtin_amdgcn_s_barrier();                                           \
  __builtin_amdgcn_sched_barrier(0)

#define ENDBAR                                                            \
  __builtin_amdgcn_sched_barrier(0);                                      \
  __builtin_amdgcn_s_barrier()

// ---------------- layer-1 GEMM body ----------------
// BM=256 rows/block, BN=128 cols; half: 0 -> Wl (P), 1 -> Wr (Q).
// d-loads issued one iteration ahead of exp consumption (R14); GBF via
// exp-RECURRENCE (R8-proven: gbf_{k+1} = gbf_k * r, r *= S -> 2 exps + 14
// muls per 8-run instead of 8 exps; bond uses 4-runs for f32 exp range).
// R14 PMC showed VALUBusy 43% = exp-bound; this cuts exp VALU ~4x.
// MODE 1: bond [N][12], K=480 (40 filters). MODE 2: angle [N][144], K=1152.
template <int MODE, int K>
__device__ __forceinline__ void gemm1_body(
    const float* __restrict__ Asrc, const f16* __restrict__ Wcat,
    f16* __restrict__ P, f16* __restrict__ Q, int n, AsT& As, BsT& Bs) {
  constexpr int CIN = (MODE == 1) ? 12 : 144;
  constexpr int NT = K / 32;
  constexpr float G2I = (MODE == 1) ? 25.0f : 16.0f;  // 1/gamma^2
  constexpr float DLT = (MODE == 1) ? (8.0f / 39.0f) : (2.0f / 7.0f);
  constexpr float C1 = 2.0f * G2I * DLT;
  constexpr float C2 = G2I * DLT * DLT;
  constexpr int RUN = (MODE == 1) ? 4 : 8;  // bond 4-runs: exp(C1*u) f32 range
  const float S = __expf(-2.0f * C2);

  const int tid = threadIdx.x;
  const int lane = tid & 63;
  const int wid = tid >> 6;
  const int wr = wid >> 1;  // 0..3 (64-row strip)
  const int wc = wid & 1;   // 0..1 (64-col strip)
  const int row0 = blockIdx.x * 256;
  const int half = blockIdx.y;
  const f16* Wh = Wcat + (size_t)half * 128 * K;
  f16* outp = half ? Q : P;

  const int bcol = tid & 127;
  const int bkb = tid >> 7;  // 0..3
  const int sArow = tid & 255;
  const int sAkb0 = tid >> 8;  // 0..1 (+2 on pass 1)
  int arow = row0 + sArow;
  if (arow >= n) arow = n - 1;

  f32x4 acc[4][4];
#pragma unroll
  for (int m = 0; m < 4; ++m)
#pragma unroll
    for (int q = 0; q < 4; ++q) acc[m][q] = (f32x4)0.f;

  auto daddr = [&](int t, int p) -> const float* {
    int kb = sAkb0 + 2 * p;
    int kg0 = t * 32 + kb * 8;
    int jn = (MODE == 1) ? kg0 / 40 : (kg0 >> 3);
    return &Asrc[(size_t)arow * CIN + jn];
  };
  auto bload = [&](int t) {
    gld_lds16(Wh + (size_t)bcol * K + t * 32 + bkb * 8, &Bs[t % 3][bkb][bcol][0]);
  };
  auto expwrite = [&](int t, const float* d2) {
#pragma unroll
    for (int p = 0; p < 2; ++p) {
      int kb = sAkb0 + 2 * p;
      int kg0 = t * 32 + kb * 8;
      float d = d2[p];
      int kk0;
      if constexpr (MODE == 1) {
        int jn = kg0 / 40;  // 40 % 8 == 0: 8-block never crosses a filter group
        kk0 = kg0 - jn * 40;
      } else {
        kk0 = 0;
      }
      f16 v[8];
#pragma unroll
      for (int h = 0; h < 8 / RUN; ++h) {
        float f0 = (float)(kk0 + h * RUN) * DLT + (MODE == 2 ? -1.0f : 0.0f);
        float u = d - f0;
        float g = __expf(-G2I * u * u);
        float ratio = __expf(C1 * u - C2);
        v[h * RUN] = (f16)g;
#pragma unroll
        for (int j = 1; j < RUN; ++j) {
          g *= ratio;
          ratio *= S;
          v[h * RUN + j] = (f16)g;
        }
      }
      *(f16x8*)&As[t % 3][kb][sArow][0] = *(const f16x8*)v;
    }
  };

  float dA[2], dB[2];
  // prologue: B for tiles 0,1 in flight; d(2) prefetched; tiles 0,1 exp inline
  bload(0);
  bload(1);
  dA[0] = *daddr(2, 0);
  dA[1] = *daddr(2, 1);
  {
    float d0[2] = {*daddr(0, 0), *daddr(0, 1)};
    expwrite(0, d0);
    float d1[2] = {*daddr(1, 0), *daddr(1, 1)};
    expwrite(1, d1);
  }

  for (int t = 0; t < NT; ++t) {
    if (t + 2 < NT) bload(t + 2);
    if (t + 3 < NT) {
      dB[0] = *daddr(t + 3, 0);
      dB[1] = *daddr(t + 3, 1);
    }
    if (t + 2 < NT) expwrite(t + 2, dA);  // implicit counted wait on dA only
    if (t < NT - 3) {
      WAITVM(3);  // newest 3 = B(t+2), d(t+3)x2 stay in flight; B(t) is landed
    } else {
      WAITVM(0);  // tail: precise drain
    }
    const int buf = t % 3;
    const int kb = lane >> 4;
    const int r16 = lane & 15;
    f16x8 a[4], b[4];
#pragma unroll
    for (int m = 0; m < 4; ++m)
      a[m] = *(const f16x8*)&As[buf][kb][wr * 64 + m * 16 + r16][0];
#pragma unroll
    for (int q = 0; q < 4; ++q)
      b[q] = *(const f16x8*)&Bs[buf][kb][wc * 64 + q * 16 + r16][0];
#pragma unroll
    for (int m = 0; m < 4; ++m)
#pragma unroll
      for (int q = 0; q < 4; ++q)
        acc[m][q] =
            __builtin_amdgcn_mfma_f32_16x16x32_f16(a[m], b[q], acc[m][q], 0, 0, 0);
    ENDBAR;  // protect buf(t%3) from stage(t+3) next iter
    dA[0] = dB[0];
    dA[1] = dB[1];
  }

  const int crow = (lane >> 4) * 4;
  const int ccol = lane & 15;
#pragma unroll
  for (int m = 0; m < 4; ++m) {
#pragma unroll
    for (int r = 0; r < 4; ++r) {
      int row = row0 + wr * 64 + m * 16 + crow + r;
      if (row < n) {
#pragma unroll
        for (int q = 0; q < 4; ++q)
          outp[(size_t)row * 128 + wc * 64 + q * 16 + ccol] = (f16)acc[m][q][r];
      }
    }
  }
}

// grid (196, 2, 2): y = W-half, z = mode (0 angle K=1152, 1 bond K=480).
__global__ __launch_bounds__(512) void gemm1all(
    const float* __restrict__ angle, const f16* __restrict__ Wa,
    f16* __restrict__ Pa, f16* __restrict__ Qa,
    const float* __restrict__ bond, const f16* __restrict__ Wb,
    f16* __restrict__ Pb, f16* __restrict__ Qb, int n) {
  __shared__ __align__(16) AsT As;
  __shared__ __align__(16) BsT Bs;
  if (blockIdx.z == 0)
    gemm1_body<2, 1152>(angle, Wa, Pa, Qa, n, As, Bs);
  else
    gemm1_body<1, 480>(bond, Wb, Pb, Qb, n, As, Bs);
}

// ---------------- layers 2-3: x' = relu([agg|x] @ Wcat2^T + b) ----------------
// BM=256, BN=128, 512 threads, IN-PLACE ax update (block-local safe).
// Per-stage vm ops: 3 gld_lds -> counted vmcnt 6/3/0.
__global__ __launch_bounds__(512) void gemmL(
    f16* __restrict__ axb, f16* __restrict__ axa, const f16* __restrict__ Wall,
    const float* __restrict__ bb, const float* __restrict__ ba, int lidx, int n) {
  __shared__ __align__(16) AsT As;
  __shared__ __align__(16) BsT Bs;
  const int path = blockIdx.y;
  f16* ax = path ? axa : axb;
  const f16* W = Wall + (size_t)(path * 2 + lidx) * 32768;
  const float* bias = (path ? ba : bb) + lidx * 128;

  const int tid = threadIdx.x;
  const int lane = tid & 63;
  const int wid = tid >> 6;
  const int wr = wid >> 1;  // 0..3
  const int wc = wid & 1;   // 0..1
  const int row0 = blockIdx.x * 256;

  const int bcol = tid & 127;
  const int bkb = tid >> 7;  // 0..3
  const int sArow = tid & 255;
  const int sAkb0 = tid >> 8;  // 0..1
  int arow = row0 + sArow;
  if (arow >= n) arow = n - 1;

  f32x4 acc[4][4];
#pragma unroll
  for (int m = 0; m < 4; ++m)
#pragma unroll
    for (int q = 0; q < 4; ++q) acc[m][q] = (f32x4)0.f;

  auto stage = [&](int buf, int t) {
    int k0 = t * 32;
    gld_lds16(W + (size_t)bcol * 256 + k0 + bkb * 8, &Bs[buf][bkb][bcol][0]);
#pragma unroll
    for (int p = 0; p < 2; ++p) {
      int kb = sAkb0 + 2 * p;
      gld_lds16(ax + (size_t)arow * 256 + k0 + kb * 8, &As[buf][kb][sArow][0]);
    }
  };

  stage(0, 0);
  stage(1, 1);
  for (int t = 0; t < 8; ++t) {
    if (t + 2 < 8) stage((t + 2) % 3, t + 2);
    if (t < 6) {
      WAITVM(6);
    } else if (t == 6) {
      WAITVM(3);
    } else {
      WAITVM(0);
    }
    const int buf = t % 3;
    const int kb = lane >> 4;
    const int r16 = lane & 15;
    f16x8 a[4], b[4];
#pragma unroll
    for (int m = 0; m < 4; ++m)
      a[m] = *(const f16x8*)&As[buf][kb][wr * 64 + m * 16 + r16][0];
#pragma unroll
    for (int q = 0; q < 4; ++q)
      b[q] = *(const f16x8*)&Bs[buf][kb][wc * 64 + q * 16 + r16][0];
#pragma unroll
    for (int m = 0; m < 4; ++m)
#pragma unroll
      for (int q = 0; q < 4; ++q)
        acc[m][q] =
            __builtin_amdgcn_mfma_f32_16x16x32_f16(a[m], b[q], acc[m][q], 0, 0, 0);
    ENDBAR;
  }

  const int crow = (lane >> 4) * 4;
  const int ccol = lane & 15;
#pragma unroll
  for (int m = 0; m < 4; ++m) {
#pragma unroll
    for (int r = 0; r < 4; ++r) {
      int row = row0 + wr * 64 + m * 16 + crow + r;
      if (row < n) {
#pragma unroll
        for (int q = 0; q < 4; ++q) {
          int col = wc * 64 + q * 16 + ccol;
          float v = acc[m][q][r] + bias[col];
          ax[(size_t)row * 256 + 128 + col] = (f16)fmaxf(v, 0.0f);
        }
      }
    }
  }
}

// ---------------- weight conversion ----------------
__global__ void cvtW(const float* __restrict__ Wl, const float* __restrict__ Wr,
                     f16* __restrict__ outp, int K) {
  int c = blockIdx.y;
  int k = blockIdx.x * 256 + threadIdx.x;
  if (k < K)
    outp[(size_t)c * K + k] =
        (f16)((c < 128) ? Wl[(size_t)c * K + k] : Wr[(size_t)(c - 128) * K + k]);
}

__global__ void cvtW_small(const float* __restrict__ Wl_b, const float* __restrict__ Wr_b,
                           const float* __restrict__ Wl_a, const float* __restrict__ Wr_a,
                           f16* __restrict__ outp) {
  int idx = blockIdx.x * 256 + threadIdx.x;  // 4*128*256
  int l = idx >> 15;
  int c = (idx >> 8) & 127;
  int k = idx & 255;
  const float* Wl = (l < 2) ? Wl_b + (size_t)l * 16384 : Wl_a + (size_t)(l - 2) * 16384;
  const float* Wr = (l < 2) ? Wr_b + (size_t)l * 16384 : Wr_a + (size_t)(l - 2) * 16384;
  float v = (k < 128) ? Wl[(size_t)c * 128 + k] : Wr[(size_t)c * 128 + (k - 128)];
  outp[idx] = (f16)v;
}

// ---------------- CSR build ----------------
__global__ void k_count(const int* __restrict__ nbr, int* __restrict__ deg) {
  int e = blockIdx.x * 256 + threadIdx.x;
  if (e < NEDGE) atomicAdd(&deg[nbr[e]], 1);
}
__global__ void k_scan1(const int* __restrict__ deg, int* __restrict__ rowptr,
                        int* __restrict__ bsum) {
  __shared__ int s[256];
  int t = threadIdx.x, i = blockIdx.x * 256 + t;
  int v = (i < N_ATOMS) ? deg[i] : 0;
  s[t] = v;
  __syncthreads();
  for (int off = 1; off < 256; off <<= 1) {
    int x = (t >= off) ? s[t - off] : 0;
    __syncthreads();
    s[t] += x;
    __syncthreads();
  }
  if (i < N_ATOMS) rowptr[i] = s[t] - v;
  if (t == 255) bsum[blockIdx.x] = s[255];
}
__global__ void k_scan2(int* __restrict__ bsum) {
  __shared__ int s[256];
  int t = threadIdx.x;
  int v = (t < NBLK) ? bsum[t] : 0;
  s[t] = v;
  __syncthreads();
  for (int off = 1; off < 256; off <<= 1) {
    int x = (t >= off) ? s[t - off] : 0;
    __syncthreads();
    s[t] += x;
    __syncthreads();
  }
  if (t < NBLK) bsum[t] = s[t] - v;
}
__global__ void k_scan3(int* __restrict__ rowptr, const int* __restrict__ bsum) {
  int i = blockIdx.x * 256 + threadIdx.x;
  if (i < N_ATOMS) rowptr[i] += bsum[blockIdx.x];
  if (i == 0) rowptr[N_ATOMS] = NEDGE;
}
// eidx stores PRE-SCALED byte offsets (src*256) for base+zext(u32) addressing.
__global__ void k_fill(const int* __restrict__ nbr, const int* __restrict__ rowptr,
                       int* __restrict__ cursor, int* __restrict__ eidx) {
  int e = blockIdx.x * 256 + threadIdx.x;
  if (e < NEDGE) {
    int dst = nbr[e];
    int pos = rowptr[dst] + atomicAdd(&cursor[dst], 1);
    eidx[pos] = (e / NEIGH) << 8;  // src atom * 256 bytes (P row)
  }
}

// ---------------- layer-1 finalize: x = relu(mean_j P[src_j] + b + Q) ----------------
__global__ __launch_bounds__(256) void gather_fin1(
    const f16* __restrict__ Pb, const f16* __restrict__ Qb,
    const f16* __restrict__ Pa, const f16* __restrict__ Qa,
    const int* __restrict__ rowptr, const int* __restrict__ eidx,
    const float* __restrict__ bias_b, const float* __restrict__ bias_a,
    f16* __restrict__ axb, f16* __restrict__ axa) {
  const int path = blockIdx.y;
  const char* Pc = (const char*)(path ? Pa : Pb);
  const f16* Q = path ? Qa : Qb;
  const float* bias = path ? bias_a : bias_b;
  f16* ax = path ? axa : axb;
  const int t = threadIdx.x;
  const int a = blockIdx.x * 16 + (t >> 4);
  const int g = (t & 15) * 8;
  const unsigned gb = (unsigned)(t & 15) * 16;
  const int s0 = rowptr[a], s1 = rowptr[a + 1];
  float acc[8];
#pragma unroll
  for (int u = 0; u < 8; ++u) acc[u] = 0.f;
  int j = s0;
  for (; j + 8 <= s1; j += 8) {
    f16x8 v[8];
#pragma unroll
    for (int u = 0; u < 8; ++u)
      v[u] = *(const f16x8*)(Pc + (size_t)((unsigned)eidx[j + u] + gb));
    f16x8 s = ((v[0] + v[1]) + (v[2] + v[3])) + ((v[4] + v[5]) + (v[6] + v[7]));
#pragma unroll
    for (int c = 0; c < 8; ++c) acc[c] += (float)s[c];
  }
  for (; j + 4 <= s1; j += 4) {
    f16x8 v0 = *(const f16x8*)(Pc + (size_t)((unsigned)eidx[j] + gb));
    f16x8 v1 = *(const f16x8*)(Pc + (size_t)((unsigned)eidx[j + 1] + gb));
    f16x8 v2 = *(const f16x8*)(Pc + (size_t)((unsigned)eidx[j + 2] + gb));
    f16x8 v3 = *(const f16x8*)(Pc + (size_t)((unsigned)eidx[j + 3] + gb));
    f16x8 s = (v0 + v1) + (v2 + v3);
#pragma unroll
    for (int c = 0; c < 8; ++c) acc[c] += (float)s[c];
  }
  for (; j < s1; ++j) {
    f16x8 v = *(const f16x8*)(Pc + (size_t)((unsigned)eidx[j] + gb));
#pragma unroll
    for (int c = 0; c < 8; ++c) acc[c] += (float)v[c];
  }
  f16x8 q = *(const f16x8*)&Q[(size_t)a * 128 + g];
  float inv = 1.0f / fmaxf((float)(s1 - s0), 1.0f);
  f16 outv[8];
#pragma unroll
  for (int u = 0; u < 8; ++u) {
    float v = acc[u] * inv + bias[g + u] + (float)q[u];
    outv[u] = (f16)fmaxf(v, 0.0f);
  }
  *(f16x8*)&ax[(size_t)a * 256 + 128 + g] = *(const f16x8*)outv;
}

// ---------------- layers 2-3 aggregation: agg half <- mean_j x[src_j] ----------------
__global__ __launch_bounds__(256) void gather_mean(
    f16* __restrict__ axb, f16* __restrict__ axa,
    const int* __restrict__ rowptr, const int* __restrict__ eidx) {
  f16* ax = blockIdx.y ? axa : axb;
  const char* axc = (const char*)ax;
  const int t = threadIdx.x;
  const int a = blockIdx.x * 16 + (t >> 4);
  const int g = (t & 15) * 8;
  const unsigned gb = 256u + (unsigned)(t & 15) * 16;
  const int s0 = rowptr[a], s1 = rowptr[a + 1];
  float acc[8];
#pragma unroll
  for (int u = 0; u < 8; ++u) acc[u] = 0.f;
  int j = s0;
  for (; j + 8 <= s1; j += 8) {
    f16x8 v[8];
#pragma unroll
    for (int u = 0; u < 8; ++u)
      v[u] = *(const f16x8*)(axc + (size_t)(((unsigned)eidx[j + u] << 1) + gb));
    f16x8 s = ((v[0] + v[1]) + (v[2] + v[3])) + ((v[4] + v[5]) + (v[6] + v[7]));
#pragma unroll
    for (int c = 0; c < 8; ++c) acc[c] += (float)s[c];
  }
  for (; j + 4 <= s1; j += 4) {
    f16x8 v0 = *(const f16x8*)(axc + (size_t)(((unsigned)eidx[j] << 1) + gb));
    f16x8 v1 = *(const f16x8*)(axc + (size_t)(((unsigned)eidx[j + 1] << 1) + gb));
    f16x8 v2 = *(const f16x8*)(axc + (size_t)(((unsigned)eidx[j + 2] << 1) + gb));
    f16x8 v3 = *(const f16x8*)(axc + (size_t)(((unsigned)eidx[j + 3] << 1) + gb));
    f16x8 s = (v0 + v1) + (v2 + v3);
#pragma unroll
    for (int c = 0; c < 8; ++c) acc[c] += (float)s[c];
  }
  for (; j < s1; ++j) {
    f16x8 v = *(const f16x8*)(axc + (size_t)(((unsigned)eidx[j] << 1) + gb));
#pragma unroll
    for (int c = 0; c < 8; ++c) acc[c] += (float)v[c];
  }
  float inv = 1.0f / fmaxf((float)(s1 - s0), 1.0f);
  f16 outv[8];
#pragma unroll
  for (int u = 0; u < 8; ++u) outv[u] = (f16)(acc[u] * inv);
  *(f16x8*)&ax[(size_t)a * 256 + g] = *(const f16x8*)outv;
}

// ---------------- head: pool -> mlp -> mlp -> fc ----------------
__global__ __launch_bounds__(256) void head_kernel(
    const f16* __restrict__ axb, const f16* __restrict__ axa,
    const int* __restrict__ crys, const float* __restrict__ W_mlp,
    const float* __restrict__ b_mlp, const float* __restrict__ W_fc,
    const float* __restrict__ b_fc, float* __restrict__ outp) {
  __shared__ float sh0[256], sh1[256];
  const int cry = blockIdx.x, c = threadIdx.x;
  const int s = crys[2 * cry], e = crys[2 * cry + 1];
  const f16* src = (c < 128) ? axb : axa;
  const int ch = c & 127;
  float sum = 0.f;
  for (int r = s; r < e; ++r) sum += (float)src[(size_t)r * 256 + 128 + ch];
  sh0[c] = sum / fmaxf((float)(e - s), 1.0f);
  __syncthreads();
  {
    const float* wrow = W_mlp + (size_t)c * 256;
    float s2 = b_mlp[c];
#pragma unroll 8
    for (int k = 0; k < 256; k += 4) {
      float4 w = *(const float4*)&wrow[k];
      s2 += sh0[k] * w.x + sh0[k + 1] * w.y + sh0[k + 2] * w.z + sh0[k + 3] * w.w;
    }
    sh1[c] = s2;
  }
  __syncthreads();
  {
    const float* wrow = W_mlp + 65536 + (size_t)c * 256;
    float s2 = b_mlp[256 + c];
#pragma unroll 8
    for (int k = 0; k < 256; k += 4) {
      float4 w = *(const float4*)&wrow[k];
      s2 += sh1[k] * w.x + sh1[k + 1] * w.y + sh1[k + 2] * w.z + sh1[k + 3] * w.w;
    }
    sh0[c] = s2;
  }
  __syncthreads();
  if (c < 2) {
    const float* wrow = W_fc + c * 256;
    float s2 = b_fc[c];
    for (int k = 0; k < 256; ++k) s2 += sh0[k] * wrow[k];
    outp[cry * 2 + c] = s2;
  }
}

extern "C" void kernel_launch(void* const* d_in, const int* in_sizes, int n_in,
                              void* d_out, int out_size, void* d_ws, size_t ws_size,
                              hipStream_t stream) {
  const float* bond  = (const float*)d_in[0];
  const float* angle = (const float*)d_in[1];
  const int*   nbr   = (const int*)d_in[3];
  const int*   crys  = (const int*)d_in[4];
  const float* Wl_b1 = (const float*)d_in[5];
  const float* Wr_b1 = (const float*)d_in[6];
  const float* b_b1  = (const float*)d_in[7];
  const float* Wl_a1 = (const float*)d_in[8];
  const float* Wr_a1 = (const float*)d_in[9];
  const float* b_a1  = (const float*)d_in[10];
  const float* Wl_b  = (const float*)d_in[11];
  const float* Wr_b  = (const float*)d_in[12];
  const float* b_b   = (const float*)d_in[13];
  const float* Wl_a  = (const float*)d_in[14];
  const float* Wr_a  = (const float*)d_in[15];
  const float* b_a   = (const float*)d_in[16];
  const float* W_mlp = (const float*)d_in[17];
  const float* b_mlp = (const float*)d_in[18];
  const float* W_fc  = (const float*)d_in[19];
  const float* b_fc  = (const float*)d_in[20];

  char* w = (char*)d_ws;
  auto alloc = [&](size_t bytes) {
    void* p = (void*)w;
    w += (bytes + 255) & ~(size_t)255;
    return p;
  };
  f16* axb = (f16*)alloc((size_t)N_ATOMS * 256 * 2);
  f16* axa = (f16*)alloc((size_t)N_ATOMS * 256 * 2);
  f16* Pb  = (f16*)alloc((size_t)N_ATOMS * 128 * 2);
  f16* Qb  = (f16*)alloc((size_t)N_ATOMS * 128 * 2);
  f16* Pa  = (f16*)alloc((size_t)N_ATOMS * 128 * 2);
  f16* Qa  = (f16*)alloc((size_t)N_ATOMS * 128 * 2);
  f16* Wb1c = (f16*)alloc((size_t)256 * 480 * 2);
  f16* Wa1c = (f16*)alloc((size_t)256 * 1152 * 2);
  f16* Wsm  = (f16*)alloc((size_t)4 * 128 * 256 * 2);
  // deg+cursor as ONE contiguous block: the single memset must cover BOTH
  // (0xAA re-poison between timed replays otherwise leaves cursor garbage).
  int* deg    = (int*)alloc((size_t)2 * N_ATOMS * 4);
  int* cursor = deg + N_ATOMS;
  int* rowptr = (int*)alloc((size_t)(N_ATOMS + 1) * 4);
  int* eidx   = (int*)alloc((size_t)NEDGE * 4);
  int* bsum   = (int*)alloc(256 * 4);

  // weights -> fp16
  cvtW<<<dim3(2, 256), 256, 0, stream>>>(Wl_b1, Wr_b1, Wb1c, 480);
  cvtW<<<dim3(5, 256), 256, 0, stream>>>(Wl_a1, Wr_a1, Wa1c, 1152);
  cvtW_small<<<512, 256, 0, stream>>>(Wl_b, Wr_b, Wl_a, Wr_a, Wsm);

  // CSR build
  hipMemsetAsync(deg, 0, (size_t)2 * N_ATOMS * 4, stream);
  k_count<<<(NEDGE + 255) / 256, 256, 0, stream>>>(nbr, deg);
  k_scan1<<<NBLK, 256, 0, stream>>>(deg, rowptr, bsum);
  k_scan2<<<1, 256, 0, stream>>>(bsum);
  k_scan3<<<NBLK, 256, 0, stream>>>(rowptr, bsum);
  k_fill<<<(NEDGE + 255) / 256, 256, 0, stream>>>(nbr, rowptr, cursor, eidx);

  const int GT = (N_ATOMS + 255) / 256;  // 196
  const int AG = N_ATOMS / 16;           // 3125

  // layer 1: single dispatch covers angle+bond x both W-halves
  gemm1all<<<dim3(GT, 2, 2), 512, 0, stream>>>(angle, Wa1c, Pa, Qa,
                                               bond, Wb1c, Pb, Qb, N_ATOMS);
  gather_fin1<<<dim3(AG, 2), 256, 0, stream>>>(Pb, Qb, Pa, Qa, rowptr, eidx,
                                               b_b1, b_a1, axb, axa);

  // layers 2-3 (aggregate-then-project, in-place ax)
  for (int l = 0; l < 2; ++l) {
    gather_mean<<<dim3(AG, 2), 256, 0, stream>>>(axb, axa, rowptr, eidx);
    gemmL<<<dim3(GT, 2), 512, 0, stream>>>(axb, axa, Wsm, b_b, b_a, l, N_ATOMS);
  }

  // head
  head_kernel<<<NCRYS, 256, 0, stream>>>(axb, axa, crys, W_mlp, b_mlp, W_fc, b_fc,
                                         (float*)d_out);
}